// Round 9
// baseline (304.326 us; speedup 1.0000x reference)
//
#include <hip/hip_runtime.h>
#include <cstdint>
#include <cstddef>

typedef unsigned short u16;
typedef __bf16 bf16x8 __attribute__((ext_vector_type(8)));
typedef float f32x4 __attribute__((ext_vector_type(4)));
typedef unsigned short u16x4 __attribute__((ext_vector_type(4)));
typedef unsigned short u16x8 __attribute__((ext_vector_type(8)));
typedef uint32_t u32x4 __attribute__((ext_vector_type(4)));
typedef __attribute__((address_space(1))) unsigned int as1_uint;
typedef __attribute__((address_space(3))) unsigned int as3_uint;

__device__ __forceinline__ u16 f2bf(float f) {
  uint32_t u = __builtin_bit_cast(uint32_t, f);
  u += 0x7FFFu + ((u >> 16) & 1u);   // RNE to bf16
  return (u16)(u >> 16);
}

// one-instruction packed f32x2 -> bf16x2 (RNE), T12 recipe
__device__ __forceinline__ uint32_t cvtpk2bf(float a, float b) {
  uint32_t r;
  asm("v_cvt_pk_bf16_f32 %0, %1, %2" : "=v"(r) : "v"(a), "v"(b));
  return r;
}

__device__ __forceinline__ float max3f(float a, float b, float c) {
  return fmaxf(fmaxf(a, b), c);   // clang fuses to v_max3_f32
}

__device__ __forceinline__ void gld_lds16(const void* g, void* l) {
  __builtin_amdgcn_global_load_lds((as1_uint*)g, (as3_uint*)l, 16, 0, 0);
}

// ---------------- cast fp32 -> bf16, 8 elems/thread ----------------
__global__ __launch_bounds__(256) void k_cast(const float* __restrict__ in,
                                              u16* __restrict__ out, int n8) {
  int i = blockIdx.x * 256 + threadIdx.x;
  if (i >= n8) return;
  const float4* p = reinterpret_cast<const float4*>(in) + (size_t)i * 2;
  float4 a = p[0], b = p[1];
  u16x8 r;
  r[0] = f2bf(a.x); r[1] = f2bf(a.y); r[2] = f2bf(a.z); r[3] = f2bf(a.w);
  r[4] = f2bf(b.x); r[5] = f2bf(b.y); r[6] = f2bf(b.z); r[7] = f2bf(b.w);
  *reinterpret_cast<u16x8*>(out + (size_t)i * 8) = r;
}

// ---------------- W [K][N] f32  ->  Wt [N][K] bf16 ----------------
__global__ __launch_bounds__(256) void k_transpose_cast(const float* __restrict__ W,
                                                        u16* __restrict__ Wt,
                                                        int K, int N) {
  __shared__ u16 tile[64][72];
  int k0 = blockIdx.y * 64, n0 = blockIdx.x * 64;
  int r = threadIdx.x >> 4;
  int c4 = (threadIdx.x & 15) * 4;
#pragma unroll
  for (int i = 0; i < 4; ++i) {
    int kk = r + i * 16;
    float4 v = *reinterpret_cast<const float4*>(W + (size_t)(k0 + kk) * N + n0 + c4);
    tile[kk][c4 + 0] = f2bf(v.x); tile[kk][c4 + 1] = f2bf(v.y);
    tile[kk][c4 + 2] = f2bf(v.z); tile[kk][c4 + 3] = f2bf(v.w);
  }
  __syncthreads();
#pragma unroll
  for (int i = 0; i < 4; ++i) {
    int nn = r + i * 16;
    u16x4 o;
    o[0] = tile[c4 + 0][nn]; o[1] = tile[c4 + 1][nn];
    o[2] = tile[c4 + 2][nn]; o[3] = tile[c4 + 3][nn];
    *reinterpret_cast<u16x4*>(Wt + (size_t)(n0 + nn) * K + k0 + c4) = o;
  }
}

// ---------------- V-part of qkv [token][2560+kvh*64+d] -> Vt_g[b][kvh][d][token] ----------------
__global__ __launch_bounds__(256) void k_transpose_v(const u16* __restrict__ qkv,
                                                     u16* __restrict__ vt) {
  __shared__ u16 tile[64][72];
  const int t0 = blockIdx.x * 64, kvh = blockIdx.y, b = blockIdx.z;
  const u16* src = qkv + ((size_t)(b * 2048) + t0) * 3072 + 2560 + kvh * 64;
  u16* dst = vt + ((size_t)(b * 8 + kvh) * 64) * 2048 + t0;
  const int r = threadIdx.x >> 3;          // 0..31
  const int c8 = (threadIdx.x & 7) * 8;    // 0..56
#pragma unroll
  for (int i = 0; i < 2; ++i) {
    int rr = r + i * 32;                   // token row
    u16x8 v = *reinterpret_cast<const u16x8*>(src + (size_t)rr * 3072 + c8);
#pragma unroll
    for (int j = 0; j < 8; ++j) tile[c8 + j][rr] = v[j];
  }
  __syncthreads();
#pragma unroll
  for (int i = 0; i < 2; ++i) {
    int rr = r + i * 32;                   // d row
    u16x8 o;
#pragma unroll
    for (int j = 0; j < 8; ++j) o[j] = tile[rr][c8 + j];
    *reinterpret_cast<u16x8*>(dst + (size_t)rr * 2048 + c8) = o;
  }
}

// ---------------- concat qkv bias ----------------
__global__ __launch_bounds__(256) void k_concat_bias(const float* __restrict__ bq,
                                                     const float* __restrict__ bk,
                                                     const float* __restrict__ bv,
                                                     float* __restrict__ out) {
  int i = blockIdx.x * 256 + threadIdx.x;
  if (i >= 3072) return;
  float v;
  if (i < 2048) v = bq[i];
  else if (i < 2560) v = bk[i - 2048];
  else v = bv[i - 2560];
  out[i] = v;
}

// ---------------- bf16 GEMM: C = (A[M][K] @ Bt[N][K]^T + bias) * colscale ----------------
// 128x128 tile, BK=64, 4 waves (2x2), 16x16x32 MFMA; T1 bijective XCD swizzle (nwg%8==0).
template <bool F32OUT>
__global__ __launch_bounds__(256) void k_gemm(const u16* __restrict__ A,
                                              const u16* __restrict__ Bt,
                                              const float* __restrict__ bias,
                                              void* __restrict__ Cout,
                                              int M, int N, int K,
                                              int scaleN, float scaleV) {
  __shared__ __align__(16) u16 As[128 * 64];
  __shared__ __align__(16) u16 Bs[128 * 64];
  // XCD-aware swizzle: blocks sharing id%8 (same XCD) cover contiguous tile range
  const int id = blockIdx.y * gridDim.x + blockIdx.x;
  const int cpx = (gridDim.x * gridDim.y) >> 3;
  const int nid = (id & 7) * cpx + (id >> 3);
  const int m0 = (nid / gridDim.x) * 128, n0 = (nid % gridDim.x) * 128;
  const int tid = threadIdx.x;
  const int l = tid & 63, w = tid >> 6;
  const int wm = w >> 1, wn = w & 1;
  const int lr = l & 15, lo = l >> 4;
  const int srow = w * 8 + (l >> 3);
  const int sc = (l & 7) ^ ((l >> 3) & 7);
  f32x4 acc[4][4] = {};
  for (int kt = 0; kt < K; kt += 64) {
    __syncthreads();
#pragma unroll
    for (int it = 0; it < 4; ++it) {
      int row = it * 32 + srow;
      gld_lds16(A + (size_t)(m0 + row) * K + kt + sc * 8,
                (char*)As + (it * 32 + w * 8) * 128);
      gld_lds16(Bt + (size_t)(n0 + row) * K + kt + sc * 8,
                (char*)Bs + (it * 32 + w * 8) * 128);
    }
    __syncthreads();
    bf16x8 af[4][2], bfr[4][2];
#pragma unroll
    for (int mi = 0; mi < 4; ++mi) {
      int row = wm * 64 + mi * 16 + lr;
#pragma unroll
      for (int ks = 0; ks < 2; ++ks) {
        int ch = (ks * 4 + lo) ^ (row & 7);
        af[mi][ks] = *reinterpret_cast<const bf16x8*>((const char*)As + row * 128 + ch * 16);
      }
    }
#pragma unroll
    for (int nj = 0; nj < 4; ++nj) {
      int row = wn * 64 + nj * 16 + lr;
#pragma unroll
      for (int ks = 0; ks < 2; ++ks) {
        int ch = (ks * 4 + lo) ^ (row & 7);
        bfr[nj][ks] = *reinterpret_cast<const bf16x8*>((const char*)Bs + row * 128 + ch * 16);
      }
    }
#pragma unroll
    for (int mi = 0; mi < 4; ++mi)
#pragma unroll
      for (int nj = 0; nj < 4; ++nj) {
        acc[mi][nj] = __builtin_amdgcn_mfma_f32_16x16x32_bf16(af[mi][0], bfr[nj][0], acc[mi][nj], 0, 0, 0);
        acc[mi][nj] = __builtin_amdgcn_mfma_f32_16x16x32_bf16(af[mi][1], bfr[nj][1], acc[mi][nj], 0, 0, 0);
      }
  }
#pragma unroll
  for (int mi = 0; mi < 4; ++mi) {
    int row = m0 + wm * 64 + mi * 16 + lo * 4;
#pragma unroll
    for (int nj = 0; nj < 4; ++nj) {
      int col = n0 + wn * 64 + nj * 16 + lr;
      float bv = bias[col];
      float scc = (col < scaleN) ? scaleV : 1.0f;
#pragma unroll
      for (int r = 0; r < 4; ++r) {
        float v = (acc[mi][nj][r] + bv) * scc;
        if (F32OUT) ((float*)Cout)[(size_t)(row + r) * N + col] = v;
        else        ((u16*)Cout)[(size_t)(row + r) * N + col] = f2bf(v);
      }
    }
  }
}

// online-softmax one 16-q group: p[16] (keys 16t+4lo+r for q=lr-ish col) -> PA frags + state
__device__ __forceinline__ void softmax_pack(float (&p)[16], float& mrun, float& lsum,
                                             f32x4 (&acc)[4], int lo,
                                             u32x4& pq0, u32x4& pq1) {
  constexpr float THR = 8.0f;
  float m0 = max3f(p[0], p[1], p[2]);
  float m1 = max3f(p[3], p[4], p[5]);
  float m2 = max3f(p[6], p[7], p[8]);
  float m3 = max3f(p[9], p[10], p[11]);
  float m4 = max3f(p[12], p[13], p[14]);
  float tm = fmaxf(max3f(m0, m1, m2), max3f(m3, m4, p[15]));
  tm = fmaxf(tm, __shfl_xor(tm, 16, 64));
  tm = fmaxf(tm, __shfl_xor(tm, 32, 64));
  if (__all(tm <= mrun + THR)) {
#pragma unroll
    for (int i = 0; i < 16; ++i) p[i] = __builtin_amdgcn_exp2f(p[i] - mrun);
  } else {
    float mnew = fmaxf(mrun, tm);
    float alpha = __builtin_amdgcn_exp2f(mrun - mnew);
    mrun = mnew;
#pragma unroll
    for (int i = 0; i < 16; ++i) p[i] = __builtin_amdgcn_exp2f(p[i] - mnew);
    lsum *= alpha;
#pragma unroll
    for (int r = 0; r < 4; ++r) {
      float ar = __shfl(alpha, lo * 4 + r, 64);
#pragma unroll
      for (int nj = 0; nj < 4; ++nj) acc[nj][r] *= ar;
    }
  }
  float rs = (((p[0] + p[1]) + (p[2] + p[3])) + ((p[4] + p[5]) + (p[6] + p[7])))
           + (((p[8] + p[9]) + (p[10] + p[11])) + ((p[12] + p[13]) + (p[14] + p[15])));
  rs += __shfl_xor(rs, 16, 64);
  rs += __shfl_xor(rs, 32, 64);
  lsum += rs;
  uint32_t w00 = cvtpk2bf(p[0], p[1]),   w01 = cvtpk2bf(p[2], p[3]);
  uint32_t w10 = cvtpk2bf(p[4], p[5]),   w11 = cvtpk2bf(p[6], p[7]);
  uint32_t w20 = cvtpk2bf(p[8], p[9]),   w21 = cvtpk2bf(p[10], p[11]);
  uint32_t w30 = cvtpk2bf(p[12], p[13]), w31 = cvtpk2bf(p[14], p[15]);
  asm volatile("v_permlane32_swap_b32 %0, %1" : "+v"(w00), "+v"(w10));
  asm volatile("v_permlane16_swap_b32 %0, %1" : "+v"(w00), "+v"(w10));
  asm volatile("v_permlane32_swap_b32 %0, %1" : "+v"(w01), "+v"(w11));
  asm volatile("v_permlane16_swap_b32 %0, %1" : "+v"(w01), "+v"(w11));
  asm volatile("v_permlane32_swap_b32 %0, %1" : "+v"(w20), "+v"(w30));
  asm volatile("v_permlane16_swap_b32 %0, %1" : "+v"(w20), "+v"(w30));
  asm volatile("v_permlane32_swap_b32 %0, %1" : "+v"(w21), "+v"(w31));
  asm volatile("v_permlane16_swap_b32 %0, %1" : "+v"(w21), "+v"(w31));
  pq0[0] = w00; pq0[1] = w01; pq0[2] = w10; pq0[3] = w11;
  pq1[0] = w20; pq1[1] = w21; pq1[2] = w30; pq1[3] = w31;
}

// ---------------- flash attention: 32 q-rows/wave, swapped-QK^T, async K+V dbuf ----------------
// grid (S/128, NQ, B); 4 waves x 32 q-rows (2 groups of 16); KVBLK=64; HD=64.
// Same K/V staging serves 2x MFMA (32/tile/wave): staging+addr VALU amortized, K/V L2 traffic halved.
__global__ __launch_bounds__(256, 4) void k_attn(const u16* __restrict__ QKV,
                                                 const u16* __restrict__ VT,
                                                 u16* __restrict__ Oa) {
  constexpr int S = 2048, LDQ = 3072;
  __shared__ __align__(16) u16 Ks[2][64 * 64];   // [key][d], chunk ^= row&7
  __shared__ __align__(16) u16 Vs[2][64 * 64];   // [d][key], chunk ^= row&7
  const int qt = blockIdx.x, h = blockIdx.y, b = blockIdx.z;
  const int kvh = h >> 2;
  const int tid = threadIdx.x, l = tid & 63, w = tid >> 6;
  const int lr = l & 15, lo = l >> 4;
  const size_t base = (size_t)b * S * LDQ;
  const u16* Qg = QKV + base + h * 64;
  const u16* Kg = QKV + base + 2048 + kvh * 64;
  const u16* Vg = VT + (size_t)(b * 8 + kvh) * 64 * 2048;
  const int qrow0 = qt * 128 + w * 32 + lr;      // group0 q-row
  const bf16x8 aq0 = *reinterpret_cast<const bf16x8*>(Qg + (size_t)qrow0 * LDQ + lo * 8);
  const bf16x8 aq1 = *reinterpret_cast<const bf16x8*>(Qg + (size_t)qrow0 * LDQ + 32 + lo * 8);
  const bf16x8 aq2 = *reinterpret_cast<const bf16x8*>(Qg + (size_t)(qrow0 + 16) * LDQ + lo * 8);
  const bf16x8 aq3 = *reinterpret_cast<const bf16x8*>(Qg + (size_t)(qrow0 + 16) * LDQ + 32 + lo * 8);
  f32x4 acc0[4] = {}, acc1[4] = {};
  float mrun0 = -1e30f, lsum0 = 0.f, mrun1 = -1e30f, lsum1 = 0.f;
  const int krow = w * 8 + (l >> 3);
  const int ksc = (l & 7) ^ ((l >> 3) & 7);
  // ---- prologue: stage tile 0 ----
  gld_lds16(Kg + (size_t)krow * LDQ + ksc * 8, (char*)Ks[0] + (w * 8) * 128);
  gld_lds16(Kg + (size_t)(32 + krow) * LDQ + ksc * 8, (char*)Ks[0] + (32 + w * 8) * 128);
  gld_lds16(Vg + (size_t)krow * 2048 + ksc * 8, (char*)Vs[0] + (w * 8) * 128);
  gld_lds16(Vg + (size_t)(32 + krow) * 2048 + ksc * 8, (char*)Vs[0] + (32 + w * 8) * 128);
  int cur = 0;
  for (int kt = 0; kt < S; kt += 64) {
    __syncthreads();   // implicit vmcnt(0): buf[cur] (K+V) ready
    if (kt + 64 < S) { // prefetch tile t+1; in flight across compute(t)
      const int nb = cur ^ 1, nk = kt + 64;
      gld_lds16(Kg + (size_t)(nk + krow) * LDQ + ksc * 8, (char*)Ks[nb] + (w * 8) * 128);
      gld_lds16(Kg + (size_t)(nk + 32 + krow) * LDQ + ksc * 8, (char*)Ks[nb] + (32 + w * 8) * 128);
      gld_lds16(Vg + (size_t)krow * 2048 + nk + ksc * 8, (char*)Vs[nb] + (w * 8) * 128);
      gld_lds16(Vg + (size_t)(32 + krow) * 2048 + nk + ksc * 8, (char*)Vs[nb] + (32 + w * 8) * 128);
    }
    // QK^T swapped, both q-groups: p0/p1[t*4+r] = S[key=16t+4lo+r][q]
    float p0[16], p1[16];
    const u16* KsC = Ks[cur];
    __builtin_amdgcn_s_setprio(1);
#pragma unroll
    for (int t = 0; t < 4; ++t) {
      const int row = t * 16 + lr;
      bf16x8 k0 = *reinterpret_cast<const bf16x8*>((const char*)KsC + row * 128 + ((lo ^ (row & 7)) * 16));
      bf16x8 k1 = *reinterpret_cast<const bf16x8*>((const char*)KsC + row * 128 + (((4 + lo) ^ (row & 7)) * 16));
      f32x4 z0 = {}, z1 = {};
      z0 = __builtin_amdgcn_mfma_f32_16x16x32_bf16(k0, aq0, z0, 0, 0, 0);
      z0 = __builtin_amdgcn_mfma_f32_16x16x32_bf16(k1, aq1, z0, 0, 0, 0);
      z1 = __builtin_amdgcn_mfma_f32_16x16x32_bf16(k0, aq2, z1, 0, 0, 0);
      z1 = __builtin_amdgcn_mfma_f32_16x16x32_bf16(k1, aq3, z1, 0, 0, 0);
#pragma unroll
      for (int r = 0; r < 4; ++r) { p0[t * 4 + r] = z0[r]; p1[t * 4 + r] = z1[r]; }
    }
    __builtin_amdgcn_s_setprio(0);
    u32x4 pq0, pq1, pq2, pq3;
    softmax_pack(p0, mrun0, lsum0, acc0, lo, pq0, pq1);
    softmax_pack(p1, mrun1, lsum1, acc1, lo, pq2, pq3);
    const bf16x8 pa0 = __builtin_bit_cast(bf16x8, pq0);
    const bf16x8 pa1 = __builtin_bit_cast(bf16x8, pq1);
    const bf16x8 pa2 = __builtin_bit_cast(bf16x8, pq2);
    const bf16x8 pa3 = __builtin_bit_cast(bf16x8, pq3);
    const u16* VsC = Vs[cur];
    __builtin_amdgcn_s_setprio(1);
#pragma unroll
    for (int nj = 0; nj < 4; ++nj) {
      const int vr = nj * 16 + lr;   // d row
      const bf16x8 bv0 = *reinterpret_cast<const bf16x8*>((const char*)VsC + vr * 128 + ((lo ^ (vr & 7)) * 16));
      const bf16x8 bv1 = *reinterpret_cast<const bf16x8*>((const char*)VsC + vr * 128 + (((4 + lo) ^ (vr & 7)) * 16));
      acc0[nj] = __builtin_amdgcn_mfma_f32_16x16x32_bf16(pa0, bv0, acc0[nj], 0, 0, 0);
      acc0[nj] = __builtin_amdgcn_mfma_f32_16x16x32_bf16(pa1, bv1, acc0[nj], 0, 0, 0);
      acc1[nj] = __builtin_amdgcn_mfma_f32_16x16x32_bf16(pa2, bv0, acc1[nj], 0, 0, 0);
      acc1[nj] = __builtin_amdgcn_mfma_f32_16x16x32_bf16(pa3, bv1, acc1[nj], 0, 0, 0);
    }
    __builtin_amdgcn_s_setprio(0);
    cur ^= 1;
  }
  float lf0[4], lf1[4];
#pragma unroll
  for (int r = 0; r < 4; ++r) {
    lf0[r] = 1.0f / __shfl(lsum0, lo * 4 + r, 64);
    lf1[r] = 1.0f / __shfl(lsum1, lo * 4 + r, 64);
  }
  const size_t orow0 = (size_t)b * S + qt * 128 + w * 32 + lo * 4;
#pragma unroll
  for (int nj = 0; nj < 4; ++nj) {
    const int col = h * 64 + nj * 16 + lr;
#pragma unroll
    for (int r = 0; r < 4; ++r) {
      Oa[(orow0 + r) * 2048 + col] = f2bf(acc0[nj][r] * lf0[r]);
      Oa[(orow0 + 16 + r) * 2048 + col] = f2bf(acc1[nj][r] * lf1[r]);
    }
  }
}

// ---------------- host ----------------
extern "C" void kernel_launch(void* const* d_in, const int* in_sizes, int n_in,
                              void* d_out, int out_size, void* d_ws, size_t ws_size,
                              hipStream_t stream) {
  const float* x  = (const float*)d_in[0];
  const float* Wq = (const float*)d_in[1];
  const float* bq = (const float*)d_in[2];
  const float* Wk = (const float*)d_in[3];
  const float* bk = (const float*)d_in[4];
  const float* Wv = (const float*)d_in[5];
  const float* bv = (const float*)d_in[6];
  const float* Wo = (const float*)d_in[7];
  const float* bo = (const float*)d_in[8];
  float* out = (float*)d_out;
  char* ws = (char*)d_ws;

  u16*   xb    = (u16*)(ws + 0);           // [4096][2048] bf16   16.78 MB (dead after QKV GEMM)
  u16*   vtg   = (u16*)(ws + 0);           // [2][8][64][2048] bf16 4 MB — aliases xb (written after GEMM)
  u16*   wqkvT = (u16*)(ws + 16777216);    // [3072][2048] bf16   12.58 MB
  u16*   woT   = (u16*)(ws + 29360128);    // [2048][2048] bf16    8.39 MB
  u16*   qkv   = (u16*)(ws + 37748736);    // [4096][3072] bf16   25.17 MB
  u16*   attn  = (u16*)(ws + 62914560);    // [4096][2048] bf16   16.78 MB
  float* bcat  = (float*)(ws + 79691776);  // [3072] f32

  const float SCL = 0.125f * 1.44269504088896341f;  // 1/sqrt(64) * log2(e)

  k_cast<<<4096, 256, 0, stream>>>(x, xb, 1048576);
  k_transpose_cast<<<dim3(32, 32), 256, 0, stream>>>(Wq, wqkvT, 2048, 2048);
  k_transpose_cast<<<dim3(8, 32), 256, 0, stream>>>(Wk, wqkvT + (size_t)2048 * 2048, 2048, 512);
  k_transpose_cast<<<dim3(8, 32), 256, 0, stream>>>(Wv, wqkvT + (size_t)2560 * 2048, 2048, 512);
  k_transpose_cast<<<dim3(32, 32), 256, 0, stream>>>(Wo, woT, 2048, 2048);
  k_concat_bias<<<12, 256, 0, stream>>>(bq, bk, bv, bcat);
  k_gemm<false><<<dim3(24, 32), 256, 0, stream>>>(xb, wqkvT, bcat, qkv, 4096, 3072, 2048, 2048, SCL);
  k_transpose_v<<<dim3(32, 8, 2), 256, 0, stream>>>(qkv, vtg);
  k_attn<<<dim3(16, 32, 2), 256, 0, stream>>>(qkv, vtg, attn);
  k_gemm<true><<<dim3(16, 32), 256, 0, stream>>>(attn, woT, bo, out, 4096, 2048, 2048, 0, 1.0f);
}

// Round 10
// 292.999 us; speedup vs baseline: 1.0387x; 1.0387x over previous
//
#include <hip/hip_runtime.h>
#include <cstdint>
#include <cstddef>

typedef unsigned short u16;
typedef __bf16 bf16x8 __attribute__((ext_vector_type(8)));
typedef float f32x4 __attribute__((ext_vector_type(4)));
typedef unsigned short u16x4 __attribute__((ext_vector_type(4)));
typedef unsigned short u16x8 __attribute__((ext_vector_type(8)));
typedef uint32_t u32x4 __attribute__((ext_vector_type(4)));
typedef __attribute__((address_space(1))) unsigned int as1_uint;
typedef __attribute__((address_space(3))) unsigned int as3_uint;

__device__ __forceinline__ u16 f2bf(float f) {
  uint32_t u = __builtin_bit_cast(uint32_t, f);
  u += 0x7FFFu + ((u >> 16) & 1u);   // RNE to bf16
  return (u16)(u >> 16);
}

// one-instruction packed f32x2 -> bf16x2 (RNE), T12 recipe
__device__ __forceinline__ uint32_t cvtpk2bf(float a, float b) {
  uint32_t r;
  asm("v_cvt_pk_bf16_f32 %0, %1, %2" : "=v"(r) : "v"(a), "v"(b));
  return r;
}

__device__ __forceinline__ float max3f(float a, float b, float c) {
  return fmaxf(fmaxf(a, b), c);   // clang fuses to v_max3_f32
}

__device__ __forceinline__ void gld_lds16(const void* g, void* l) {
  __builtin_amdgcn_global_load_lds((as1_uint*)g, (as3_uint*)l, 16, 0, 0);
}

// ---------------- cast fp32 -> bf16, 8 elems/thread ----------------
__global__ __launch_bounds__(256) void k_cast(const float* __restrict__ in,
                                              u16* __restrict__ out, int n8) {
  int i = blockIdx.x * 256 + threadIdx.x;
  if (i >= n8) return;
  const float4* p = reinterpret_cast<const float4*>(in) + (size_t)i * 2;
  float4 a = p[0], b = p[1];
  u16x8 r;
  r[0] = f2bf(a.x); r[1] = f2bf(a.y); r[2] = f2bf(a.z); r[3] = f2bf(a.w);
  r[4] = f2bf(b.x); r[5] = f2bf(b.y); r[6] = f2bf(b.z); r[7] = f2bf(b.w);
  *reinterpret_cast<u16x8*>(out + (size_t)i * 8) = r;
}

// ---------------- all 4 weight transposes in one launch ----------------
// z=0: Wq -> wqkvT[0..2048); z=1: Wo -> woT; z=2: Wk -> wqkvT[2048..2560);
// z=3: Wv -> wqkvT[2560..3072). K=2048 for all. grid (32,32,4); surplus blocks exit.
__global__ __launch_bounds__(256) void k_transpose_all(const float* __restrict__ Wq,
                                                       const float* __restrict__ Wk,
                                                       const float* __restrict__ Wv,
                                                       const float* __restrict__ Wo,
                                                       u16* __restrict__ wqkvT,
                                                       u16* __restrict__ woT) {
  constexpr int K = 2048;
  const int z = blockIdx.z;
  const float* W; u16* Wt; int N;
  if (z == 0)      { W = Wq; Wt = wqkvT;                        N = 2048; }
  else if (z == 1) { W = Wo; Wt = woT;                          N = 2048; }
  else if (z == 2) { W = Wk; Wt = wqkvT + (size_t)2048 * 2048;  N = 512;  }
  else             { W = Wv; Wt = wqkvT + (size_t)2560 * 2048;  N = 512;  }
  const int n0 = blockIdx.x * 64;
  if (n0 >= N) return;
  __shared__ u16 tile[64][72];
  const int k0 = blockIdx.y * 64;
  const int r = threadIdx.x >> 4;
  const int c4 = (threadIdx.x & 15) * 4;
#pragma unroll
  for (int i = 0; i < 4; ++i) {
    int kk = r + i * 16;
    float4 v = *reinterpret_cast<const float4*>(W + (size_t)(k0 + kk) * N + n0 + c4);
    tile[kk][c4 + 0] = f2bf(v.x); tile[kk][c4 + 1] = f2bf(v.y);
    tile[kk][c4 + 2] = f2bf(v.z); tile[kk][c4 + 3] = f2bf(v.w);
  }
  __syncthreads();
#pragma unroll
  for (int i = 0; i < 4; ++i) {
    int nn = r + i * 16;
    u16x4 o;
    o[0] = tile[c4 + 0][nn]; o[1] = tile[c4 + 1][nn];
    o[2] = tile[c4 + 2][nn]; o[3] = tile[c4 + 3][nn];
    *reinterpret_cast<u16x4*>(Wt + (size_t)(n0 + nn) * K + k0 + c4) = o;
  }
}

// ---------------- V-part of qkv [token][2560+kvh*64+d] -> Vt_g[b][kvh][d][token] ----------------
__global__ __launch_bounds__(256) void k_transpose_v(const u16* __restrict__ qkv,
                                                     u16* __restrict__ vt) {
  __shared__ u16 tile[64][72];
  const int t0 = blockIdx.x * 64, kvh = blockIdx.y, b = blockIdx.z;
  const u16* src = qkv + ((size_t)(b * 2048) + t0) * 3072 + 2560 + kvh * 64;
  u16* dst = vt + ((size_t)(b * 8 + kvh) * 64) * 2048 + t0;
  const int r = threadIdx.x >> 3;          // 0..31
  const int c8 = (threadIdx.x & 7) * 8;    // 0..56
#pragma unroll
  for (int i = 0; i < 2; ++i) {
    int rr = r + i * 32;                   // token row
    u16x8 v = *reinterpret_cast<const u16x8*>(src + (size_t)rr * 3072 + c8);
#pragma unroll
    for (int j = 0; j < 8; ++j) tile[c8 + j][rr] = v[j];
  }
  __syncthreads();
#pragma unroll
  for (int i = 0; i < 2; ++i) {
    int rr = r + i * 32;                   // d row
    u16x8 o;
#pragma unroll
    for (int j = 0; j < 8; ++j) o[j] = tile[rr][c8 + j];
    *reinterpret_cast<u16x8*>(dst + (size_t)rr * 2048 + c8) = o;
  }
}

// ---------------- bf16 GEMM: C = (A @ Bt^T + bias(col)) * colscale ----------------
// 128x128 tile, BK=64, 4 waves (2x2), 16x16x32 MFMA; T1 bijective XCD swizzle (nwg%8==0).
// bias: col<n1 -> b0[col]; col<n2 -> b1[col-n1]; else b2[col-n2] (kills concat launch).
template <bool F32OUT>
__global__ __launch_bounds__(256) void k_gemm(const u16* __restrict__ A,
                                              const u16* __restrict__ Bt,
                                              const float* __restrict__ b0,
                                              const float* __restrict__ b1,
                                              const float* __restrict__ b2,
                                              void* __restrict__ Cout,
                                              int M, int N, int K,
                                              int n1, int n2,
                                              int scaleN, float scaleV) {
  __shared__ __align__(16) u16 As[128 * 64];
  __shared__ __align__(16) u16 Bs[128 * 64];
  // XCD-aware swizzle: blocks sharing id%8 (same XCD) cover contiguous tile range
  const int id = blockIdx.y * gridDim.x + blockIdx.x;
  const int cpx = (gridDim.x * gridDim.y) >> 3;
  const int nid = (id & 7) * cpx + (id >> 3);
  const int m0 = (nid / gridDim.x) * 128, n0 = (nid % gridDim.x) * 128;
  const int tid = threadIdx.x;
  const int l = tid & 63, w = tid >> 6;
  const int wm = w >> 1, wn = w & 1;
  const int lr = l & 15, lo = l >> 4;
  const int srow = w * 8 + (l >> 3);
  const int sc = (l & 7) ^ ((l >> 3) & 7);
  f32x4 acc[4][4] = {};
  for (int kt = 0; kt < K; kt += 64) {
    __syncthreads();
#pragma unroll
    for (int it = 0; it < 4; ++it) {
      int row = it * 32 + srow;
      gld_lds16(A + (size_t)(m0 + row) * K + kt + sc * 8,
                (char*)As + (it * 32 + w * 8) * 128);
      gld_lds16(Bt + (size_t)(n0 + row) * K + kt + sc * 8,
                (char*)Bs + (it * 32 + w * 8) * 128);
    }
    __syncthreads();
    bf16x8 af[4][2], bfr[4][2];
#pragma unroll
    for (int mi = 0; mi < 4; ++mi) {
      int row = wm * 64 + mi * 16 + lr;
#pragma unroll
      for (int ks = 0; ks < 2; ++ks) {
        int ch = (ks * 4 + lo) ^ (row & 7);
        af[mi][ks] = *reinterpret_cast<const bf16x8*>((const char*)As + row * 128 + ch * 16);
      }
    }
#pragma unroll
    for (int nj = 0; nj < 4; ++nj) {
      int row = wn * 64 + nj * 16 + lr;
#pragma unroll
      for (int ks = 0; ks < 2; ++ks) {
        int ch = (ks * 4 + lo) ^ (row & 7);
        bfr[nj][ks] = *reinterpret_cast<const bf16x8*>((const char*)Bs + row * 128 + ch * 16);
      }
    }
#pragma unroll
    for (int mi = 0; mi < 4; ++mi)
#pragma unroll
      for (int nj = 0; nj < 4; ++nj) {
        acc[mi][nj] = __builtin_amdgcn_mfma_f32_16x16x32_bf16(af[mi][0], bfr[nj][0], acc[mi][nj], 0, 0, 0);
        acc[mi][nj] = __builtin_amdgcn_mfma_f32_16x16x32_bf16(af[mi][1], bfr[nj][1], acc[mi][nj], 0, 0, 0);
      }
  }
#pragma unroll
  for (int mi = 0; mi < 4; ++mi) {
    int row = m0 + wm * 64 + mi * 16 + lo * 4;
#pragma unroll
    for (int nj = 0; nj < 4; ++nj) {
      int col = n0 + wn * 64 + nj * 16 + lr;
      float bv = (col < n1) ? b0[col] : (col < n2 ? b1[col - n1] : b2[col - n2]);
      float scc = (col < scaleN) ? scaleV : 1.0f;
#pragma unroll
      for (int r = 0; r < 4; ++r) {
        float v = (acc[mi][nj][r] + bv) * scc;
        if (F32OUT) ((float*)Cout)[(size_t)(row + r) * N + col] = v;
        else        ((u16*)Cout)[(size_t)(row + r) * N + col] = f2bf(v);
      }
    }
  }
}

// ---------------- flash attention: swapped-QK^T, in-register P, async K+V dbuf ----------------
// grid (S/64, NQ, B); 4 waves x 16 q-rows; KVBLK=64; HD=64; launch_bounds(256,4).
// R8 configuration (VGPR 52 — fits hipcc's 64-cap at waves=4; R9's 32q/wave spilled).
__global__ __launch_bounds__(256, 4) void k_attn(const u16* __restrict__ QKV,
                                                 const u16* __restrict__ VT,
                                                 u16* __restrict__ Oa) {
  constexpr int S = 2048, LDQ = 3072;
  constexpr float THR = 8.0f;
  __shared__ __align__(16) u16 Ks[2][64 * 64];   // [key][d], chunk ^= row&7
  __shared__ __align__(16) u16 Vs[2][64 * 64];   // [d][key], chunk ^= row&7
  const int qt = blockIdx.x, h = blockIdx.y, b = blockIdx.z;
  const int kvh = h >> 2;
  const int tid = threadIdx.x, l = tid & 63, w = tid >> 6;
  const int lr = l & 15, lo = l >> 4;
  const size_t base = (size_t)b * S * LDQ;
  const u16* Qg = QKV + base + h * 64;
  const u16* Kg = QKV + base + 2048 + kvh * 64;
  const u16* Vg = VT + (size_t)(b * 8 + kvh) * 64 * 2048;
  const int qrow = qt * 64 + w * 16 + lr;
  const bf16x8 aq0 = *reinterpret_cast<const bf16x8*>(Qg + (size_t)qrow * LDQ + lo * 8);
  const bf16x8 aq1 = *reinterpret_cast<const bf16x8*>(Qg + (size_t)qrow * LDQ + 32 + lo * 8);
  f32x4 acc[4] = {};
  float mrun = -1e30f, lsum = 0.f;
  const int krow = w * 8 + (l >> 3);
  const int ksc = (l & 7) ^ ((l >> 3) & 7);
  // ---- prologue: stage tile 0 ----
  gld_lds16(Kg + (size_t)krow * LDQ + ksc * 8, (char*)Ks[0] + (w * 8) * 128);
  gld_lds16(Kg + (size_t)(32 + krow) * LDQ + ksc * 8, (char*)Ks[0] + (32 + w * 8) * 128);
  gld_lds16(Vg + (size_t)krow * 2048 + ksc * 8, (char*)Vs[0] + (w * 8) * 128);
  gld_lds16(Vg + (size_t)(32 + krow) * 2048 + ksc * 8, (char*)Vs[0] + (32 + w * 8) * 128);
  int cur = 0;
  for (int kt = 0; kt < S; kt += 64) {
    __syncthreads();   // implicit vmcnt(0): buf[cur] (K+V) ready
    if (kt + 64 < S) { // prefetch tile t+1; in flight across compute(t)
      const int nb = cur ^ 1, nk = kt + 64;
      gld_lds16(Kg + (size_t)(nk + krow) * LDQ + ksc * 8, (char*)Ks[nb] + (w * 8) * 128);
      gld_lds16(Kg + (size_t)(nk + 32 + krow) * LDQ + ksc * 8, (char*)Ks[nb] + (32 + w * 8) * 128);
      gld_lds16(Vg + (size_t)krow * 2048 + nk + ksc * 8, (char*)Vs[nb] + (w * 8) * 128);
      gld_lds16(Vg + (size_t)(32 + krow) * 2048 + nk + ksc * 8, (char*)Vs[nb] + (32 + w * 8) * 128);
    }
    // QK^T swapped: p[t*4+r] = S[key=16t+4lo+r][q=lr]  (Q pre-scaled by log2e/sqrt(HD))
    float p[16];
    const u16* KsC = Ks[cur];
    __builtin_amdgcn_s_setprio(1);
#pragma unroll
    for (int t = 0; t < 4; ++t) {
      const int row = t * 16 + lr;
      bf16x8 k0 = *reinterpret_cast<const bf16x8*>((const char*)KsC + row * 128 + ((lo ^ (row & 7)) * 16));
      bf16x8 k1 = *reinterpret_cast<const bf16x8*>((const char*)KsC + row * 128 + (((4 + lo) ^ (row & 7)) * 16));
      f32x4 zz = {};
      zz = __builtin_amdgcn_mfma_f32_16x16x32_bf16(k0, aq0, zz, 0, 0, 0);
      zz = __builtin_amdgcn_mfma_f32_16x16x32_bf16(k1, aq1, zz, 0, 0, 0);
#pragma unroll
      for (int r = 0; r < 4; ++r) p[t * 4 + r] = zz[r];
    }
    __builtin_amdgcn_s_setprio(0);
    // tile max for q=lr: max3 tree + 2 shfl
    float m0 = max3f(p[0], p[1], p[2]);
    float m1 = max3f(p[3], p[4], p[5]);
    float m2 = max3f(p[6], p[7], p[8]);
    float m3 = max3f(p[9], p[10], p[11]);
    float m4 = max3f(p[12], p[13], p[14]);
    float tm = fmaxf(max3f(m0, m1, m2), max3f(m3, m4, p[15]));
    tm = fmaxf(tm, __shfl_xor(tm, 16, 64));
    tm = fmaxf(tm, __shfl_xor(tm, 32, 64));
    if (__all(tm <= mrun + THR)) {
      // defer-max: keep stale mrun; p bounded by 2^THR
#pragma unroll
      for (int i = 0; i < 16; ++i) p[i] = __builtin_amdgcn_exp2f(p[i] - mrun);
    } else {
      float mnew = fmaxf(mrun, tm);
      float alpha = __builtin_amdgcn_exp2f(mrun - mnew);
      mrun = mnew;
#pragma unroll
      for (int i = 0; i < 16; ++i) p[i] = __builtin_amdgcn_exp2f(p[i] - mnew);
      lsum *= alpha;
#pragma unroll
      for (int r = 0; r < 4; ++r) {
        float ar = __shfl(alpha, lo * 4 + r, 64);   // alpha for acc-row q=lo*4+r
#pragma unroll
        for (int nj = 0; nj < 4; ++nj) acc[nj][r] *= ar;
      }
    }
    float rs = (((p[0] + p[1]) + (p[2] + p[3])) + ((p[4] + p[5]) + (p[6] + p[7])))
             + (((p[8] + p[9]) + (p[10] + p[11])) + ((p[12] + p[13]) + (p[14] + p[15])));
    rs += __shfl_xor(rs, 16, 64);
    rs += __shfl_xor(rs, 32, 64);
    lsum += rs;
    // pack P pairs with v_cvt_pk_bf16_f32 (1 instr each)
    uint32_t w00 = cvtpk2bf(p[0], p[1]),   w01 = cvtpk2bf(p[2], p[3]);
    uint32_t w10 = cvtpk2bf(p[4], p[5]),   w11 = cvtpk2bf(p[6], p[7]);
    uint32_t w20 = cvtpk2bf(p[8], p[9]),   w21 = cvtpk2bf(p[10], p[11]);
    uint32_t w30 = cvtpk2bf(p[12], p[13]), w31 = cvtpk2bf(p[14], p[15]);
    // redistribute to A-frag layout: lane lo needs keys 8lo..8lo+7 (pa0), +32 (pa1)
    asm volatile("v_permlane32_swap_b32 %0, %1" : "+v"(w00), "+v"(w10));
    asm volatile("v_permlane16_swap_b32 %0, %1" : "+v"(w00), "+v"(w10));  // w00=d0 w10=d2
    asm volatile("v_permlane32_swap_b32 %0, %1" : "+v"(w01), "+v"(w11));
    asm volatile("v_permlane16_swap_b32 %0, %1" : "+v"(w01), "+v"(w11));  // w01=d1 w11=d3
    asm volatile("v_permlane32_swap_b32 %0, %1" : "+v"(w20), "+v"(w30));
    asm volatile("v_permlane16_swap_b32 %0, %1" : "+v"(w20), "+v"(w30));
    asm volatile("v_permlane32_swap_b32 %0, %1" : "+v"(w21), "+v"(w31));
    asm volatile("v_permlane16_swap_b32 %0, %1" : "+v"(w21), "+v"(w31));
    u32x4 pq0; pq0[0] = w00; pq0[1] = w01; pq0[2] = w10; pq0[3] = w11;
    u32x4 pq1; pq1[0] = w20; pq1[1] = w21; pq1[2] = w30; pq1[3] = w31;
    const bf16x8 pa0 = __builtin_bit_cast(bf16x8, pq0);
    const bf16x8 pa1 = __builtin_bit_cast(bf16x8, pq1);
    const u16* VsC = Vs[cur];
    __builtin_amdgcn_s_setprio(1);
#pragma unroll
    for (int nj = 0; nj < 4; ++nj) {
      const int vr = nj * 16 + lr;   // d row
      const bf16x8 bv0 = *reinterpret_cast<const bf16x8*>((const char*)VsC + vr * 128 + ((lo ^ (vr & 7)) * 16));
      const bf16x8 bv1 = *reinterpret_cast<const bf16x8*>((const char*)VsC + vr * 128 + (((4 + lo) ^ (vr & 7)) * 16));
      acc[nj] = __builtin_amdgcn_mfma_f32_16x16x32_bf16(pa0, bv0, acc[nj], 0, 0, 0);
      acc[nj] = __builtin_amdgcn_mfma_f32_16x16x32_bf16(pa1, bv1, acc[nj], 0, 0, 0);
    }
    __builtin_amdgcn_s_setprio(0);
    cur ^= 1;
  }
  float lf[4];
#pragma unroll
  for (int r = 0; r < 4; ++r) lf[r] = 1.0f / __shfl(lsum, lo * 4 + r, 64);
  const size_t orow = (size_t)b * S + qt * 64 + w * 16 + lo * 4;
#pragma unroll
  for (int nj = 0; nj < 4; ++nj) {
    const int col = h * 64 + nj * 16 + lr;
#pragma unroll
    for (int r = 0; r < 4; ++r)
      Oa[(orow + r) * 2048 + col] = f2bf(acc[nj][r] * lf[r]);
  }
}

// ---------------- host ----------------
extern "C" void kernel_launch(void* const* d_in, const int* in_sizes, int n_in,
                              void* d_out, int out_size, void* d_ws, size_t ws_size,
                              hipStream_t stream) {
  const float* x  = (const float*)d_in[0];
  const float* Wq = (const float*)d_in[1];
  const float* bq = (const float*)d_in[2];
  const float* Wk = (const float*)d_in[3];
  const float* bk = (const float*)d_in[4];
  const float* Wv = (const float*)d_in[5];
  const float* bv = (const float*)d_in[6];
  const float* Wo = (const float*)d_in[7];
  const float* bo = (const float*)d_in[8];
  float* out = (float*)d_out;
  char* ws = (char*)d_ws;

  u16*   xb    = (u16*)(ws + 0);           // [4096][2048] bf16   16.78 MB (dead after QKV GEMM)
  u16*   vtg   = (u16*)(ws + 0);           // [2][8][64][2048] bf16 4 MB — aliases xb (written after GEMM)
  u16*   wqkvT = (u16*)(ws + 16777216);    // [3072][2048] bf16   12.58 MB
  u16*   woT   = (u16*)(ws + 29360128);    // [2048][2048] bf16    8.39 MB
  u16*   qkv   = (u16*)(ws + 37748736);    // [4096][3072] bf16   25.17 MB
  u16*   attn  = (u16*)(ws + 62914560);    // [4096][2048] bf16   16.78 MB

  const float SCL = 0.125f * 1.44269504088896341f;  // 1/sqrt(64) * log2(e)

  k_cast<<<4096, 256, 0, stream>>>(x, xb, 1048576);
  k_transpose_all<<<dim3(32, 32, 4), 256, 0, stream>>>(Wq, Wk, Wv, Wo, wqkvT, woT);
  k_gemm<false><<<dim3(24, 32), 256, 0, stream>>>(xb, wqkvT, bq, bk, bv, qkv,
                                                  4096, 3072, 2048, 2048, 2560, 2048, SCL);
  k_transpose_v<<<dim3(32, 8, 2), 256, 0, stream>>>(qkv, vtg);
  k_attn<<<dim3(32, 32, 2), 256, 0, stream>>>(qkv, vtg, attn);
  k_gemm<true><<<dim3(16, 32), 256, 0, stream>>>(attn, woT, bo, bo, bo, out,
                                                 4096, 2048, 2048, 2048, 4096, 0, 1.0f);
}

// Round 11
// 288.761 us; speedup vs baseline: 1.0539x; 1.0147x over previous
//
#include <hip/hip_runtime.h>
#include <cstdint>
#include <cstddef>

typedef unsigned short u16;
typedef __bf16 bf16x8 __attribute__((ext_vector_type(8)));
typedef float f32x4 __attribute__((ext_vector_type(4)));
typedef unsigned short u16x4 __attribute__((ext_vector_type(4)));
typedef unsigned short u16x8 __attribute__((ext_vector_type(8)));
typedef uint32_t u32x4 __attribute__((ext_vector_type(4)));
typedef __attribute__((address_space(1))) unsigned int as1_uint;
typedef __attribute__((address_space(3))) unsigned int as3_uint;

__device__ __forceinline__ u16 f2bf(float f) {
  uint32_t u = __builtin_bit_cast(uint32_t, f);
  u += 0x7FFFu + ((u >> 16) & 1u);   // RNE to bf16
  return (u16)(u >> 16);
}

// one-instruction packed f32x2 -> bf16x2 (RNE), T12 recipe
__device__ __forceinline__ uint32_t cvtpk2bf(float a, float b) {
  uint32_t r;
  asm("v_cvt_pk_bf16_f32 %0, %1, %2" : "=v"(r) : "v"(a), "v"(b));
  return r;
}

__device__ __forceinline__ float max3f(float a, float b, float c) {
  return fmaxf(fmaxf(a, b), c);   // clang fuses to v_max3_f32
}

__device__ __forceinline__ void gld_lds16(const void* g, void* l) {
  __builtin_amdgcn_global_load_lds((as1_uint*)g, (as3_uint*)l, 16, 0, 0);
}

// ---------------- cast fp32 -> bf16, 8 elems/thread ----------------
__global__ __launch_bounds__(256) void k_cast(const float* __restrict__ in,
                                              u16* __restrict__ out, int n8) {
  int i = blockIdx.x * 256 + threadIdx.x;
  if (i >= n8) return;
  const float4* p = reinterpret_cast<const float4*>(in) + (size_t)i * 2;
  float4 a = p[0], b = p[1];
  u16x8 r;
  r[0] = f2bf(a.x); r[1] = f2bf(a.y); r[2] = f2bf(a.z); r[3] = f2bf(a.w);
  r[4] = f2bf(b.x); r[5] = f2bf(b.y); r[6] = f2bf(b.z); r[7] = f2bf(b.w);
  *reinterpret_cast<u16x8*>(out + (size_t)i * 8) = r;
}

// ---------------- all 4 weight transposes in one launch ----------------
__global__ __launch_bounds__(256) void k_transpose_all(const float* __restrict__ Wq,
                                                       const float* __restrict__ Wk,
                                                       const float* __restrict__ Wv,
                                                       const float* __restrict__ Wo,
                                                       u16* __restrict__ wqkvT,
                                                       u16* __restrict__ woT) {
  constexpr int K = 2048;
  const int z = blockIdx.z;
  const float* W; u16* Wt; int N;
  if (z == 0)      { W = Wq; Wt = wqkvT;                        N = 2048; }
  else if (z == 1) { W = Wo; Wt = woT;                          N = 2048; }
  else if (z == 2) { W = Wk; Wt = wqkvT + (size_t)2048 * 2048;  N = 512;  }
  else             { W = Wv; Wt = wqkvT + (size_t)2560 * 2048;  N = 512;  }
  const int n0 = blockIdx.x * 64;
  if (n0 >= N) return;
  __shared__ u16 tile[64][72];
  const int k0 = blockIdx.y * 64;
  const int r = threadIdx.x >> 4;
  const int c4 = (threadIdx.x & 15) * 4;
#pragma unroll
  for (int i = 0; i < 4; ++i) {
    int kk = r + i * 16;
    float4 v = *reinterpret_cast<const float4*>(W + (size_t)(k0 + kk) * N + n0 + c4);
    tile[kk][c4 + 0] = f2bf(v.x); tile[kk][c4 + 1] = f2bf(v.y);
    tile[kk][c4 + 2] = f2bf(v.z); tile[kk][c4 + 3] = f2bf(v.w);
  }
  __syncthreads();
#pragma unroll
  for (int i = 0; i < 4; ++i) {
    int nn = r + i * 16;
    u16x4 o;
    o[0] = tile[c4 + 0][nn]; o[1] = tile[c4 + 1][nn];
    o[2] = tile[c4 + 2][nn]; o[3] = tile[c4 + 3][nn];
    *reinterpret_cast<u16x4*>(Wt + (size_t)(n0 + nn) * K + k0 + c4) = o;
  }
}

// ---------------- V-part of qkv -> Vt_g[b][kvh][d][token] ----------------
__global__ __launch_bounds__(256) void k_transpose_v(const u16* __restrict__ qkv,
                                                     u16* __restrict__ vt) {
  __shared__ u16 tile[64][72];
  const int t0 = blockIdx.x * 64, kvh = blockIdx.y, b = blockIdx.z;
  const u16* src = qkv + ((size_t)(b * 2048) + t0) * 3072 + 2560 + kvh * 64;
  u16* dst = vt + ((size_t)(b * 8 + kvh) * 64) * 2048 + t0;
  const int r = threadIdx.x >> 3;          // 0..31
  const int c8 = (threadIdx.x & 7) * 8;    // 0..56
#pragma unroll
  for (int i = 0; i < 2; ++i) {
    int rr = r + i * 32;                   // token row
    u16x8 v = *reinterpret_cast<const u16x8*>(src + (size_t)rr * 3072 + c8);
#pragma unroll
    for (int j = 0; j < 8; ++j) tile[c8 + j][rr] = v[j];
  }
  __syncthreads();
#pragma unroll
  for (int i = 0; i < 2; ++i) {
    int rr = r + i * 32;                   // d row
    u16x8 o;
#pragma unroll
    for (int j = 0; j < 8; ++j) o[j] = tile[rr][c8 + j];
    *reinterpret_cast<u16x8*>(dst + (size_t)rr * 2048 + c8) = o;
  }
}

// ---------------- bf16 GEMM: C = (A @ Bt^T + bias(col)) * colscale ----------------
// 128x128 tile, BK=64, 4 waves (2x2), 16x16x32 MFMA; T1 bijective XCD swizzle (nwg%8==0).
template <bool F32OUT>
__global__ __launch_bounds__(256) void k_gemm(const u16* __restrict__ A,
                                              const u16* __restrict__ Bt,
                                              const float* __restrict__ b0,
                                              const float* __restrict__ b1,
                                              const float* __restrict__ b2,
                                              void* __restrict__ Cout,
                                              int M, int N, int K,
                                              int n1, int n2,
                                              int scaleN, float scaleV) {
  __shared__ __align__(16) u16 As[128 * 64];
  __shared__ __align__(16) u16 Bs[128 * 64];
  const int id = blockIdx.y * gridDim.x + blockIdx.x;
  const int cpx = (gridDim.x * gridDim.y) >> 3;
  const int nid = (id & 7) * cpx + (id >> 3);
  const int m0 = (nid / gridDim.x) * 128, n0 = (nid % gridDim.x) * 128;
  const int tid = threadIdx.x;
  const int l = tid & 63, w = tid >> 6;
  const int wm = w >> 1, wn = w & 1;
  const int lr = l & 15, lo = l >> 4;
  const int srow = w * 8 + (l >> 3);
  const int sc = (l & 7) ^ ((l >> 3) & 7);
  f32x4 acc[4][4] = {};
  for (int kt = 0; kt < K; kt += 64) {
    __syncthreads();
#pragma unroll
    for (int it = 0; it < 4; ++it) {
      int row = it * 32 + srow;
      gld_lds16(A + (size_t)(m0 + row) * K + kt + sc * 8,
                (char*)As + (it * 32 + w * 8) * 128);
      gld_lds16(Bt + (size_t)(n0 + row) * K + kt + sc * 8,
                (char*)Bs + (it * 32 + w * 8) * 128);
    }
    __syncthreads();
    bf16x8 af[4][2], bfr[4][2];
#pragma unroll
    for (int mi = 0; mi < 4; ++mi) {
      int row = wm * 64 + mi * 16 + lr;
#pragma unroll
      for (int ks = 0; ks < 2; ++ks) {
        int ch = (ks * 4 + lo) ^ (row & 7);
        af[mi][ks] = *reinterpret_cast<const bf16x8*>((const char*)As + row * 128 + ch * 16);
      }
    }
#pragma unroll
    for (int nj = 0; nj < 4; ++nj) {
      int row = wn * 64 + nj * 16 + lr;
#pragma unroll
      for (int ks = 0; ks < 2; ++ks) {
        int ch = (ks * 4 + lo) ^ (row & 7);
        bfr[nj][ks] = *reinterpret_cast<const bf16x8*>((const char*)Bs + row * 128 + ch * 16);
      }
    }
#pragma unroll
    for (int mi = 0; mi < 4; ++mi)
#pragma unroll
      for (int nj = 0; nj < 4; ++nj) {
        acc[mi][nj] = __builtin_amdgcn_mfma_f32_16x16x32_bf16(af[mi][0], bfr[nj][0], acc[mi][nj], 0, 0, 0);
        acc[mi][nj] = __builtin_amdgcn_mfma_f32_16x16x32_bf16(af[mi][1], bfr[nj][1], acc[mi][nj], 0, 0, 0);
      }
  }
#pragma unroll
  for (int mi = 0; mi < 4; ++mi) {
    int row = m0 + wm * 64 + mi * 16 + lo * 4;
#pragma unroll
    for (int nj = 0; nj < 4; ++nj) {
      int col = n0 + wn * 64 + nj * 16 + lr;
      float bv = (col < n1) ? b0[col] : (col < n2 ? b1[col - n1] : b2[col - n2]);
      float scc = (col < scaleN) ? scaleV : 1.0f;
#pragma unroll
      for (int r = 0; r < 4; ++r) {
        float v = (acc[mi][nj][r] + bv) * scc;
        if (F32OUT) ((float*)Cout)[(size_t)(row + r) * N + col] = v;
        else        ((u16*)Cout)[(size_t)(row + r) * N + col] = f2bf(v);
      }
    }
  }
}

// online-softmax one 16-q group -> PA frags + state (verified R8/R10 math)
__device__ __forceinline__ void softmax_pack(float (&p)[16], float& mrun, float& lsum,
                                             f32x4 (&acc)[4], int lo,
                                             u32x4& pq0, u32x4& pq1) {
  constexpr float THR = 8.0f;
  float m0 = max3f(p[0], p[1], p[2]);
  float m1 = max3f(p[3], p[4], p[5]);
  float m2 = max3f(p[6], p[7], p[8]);
  float m3 = max3f(p[9], p[10], p[11]);
  float m4 = max3f(p[12], p[13], p[14]);
  float tm = fmaxf(max3f(m0, m1, m2), max3f(m3, m4, p[15]));
  tm = fmaxf(tm, __shfl_xor(tm, 16, 64));
  tm = fmaxf(tm, __shfl_xor(tm, 32, 64));
  if (__all(tm <= mrun + THR)) {
#pragma unroll
    for (int i = 0; i < 16; ++i) p[i] = __builtin_amdgcn_exp2f(p[i] - mrun);
  } else {
    float mnew = fmaxf(mrun, tm);
    float alpha = __builtin_amdgcn_exp2f(mrun - mnew);
    mrun = mnew;
#pragma unroll
    for (int i = 0; i < 16; ++i) p[i] = __builtin_amdgcn_exp2f(p[i] - mnew);
    lsum *= alpha;
#pragma unroll
    for (int r = 0; r < 4; ++r) {
      float ar = __shfl(alpha, lo * 4 + r, 64);
#pragma unroll
      for (int nj = 0; nj < 4; ++nj) acc[nj][r] *= ar;
    }
  }
  float rs = (((p[0] + p[1]) + (p[2] + p[3])) + ((p[4] + p[5]) + (p[6] + p[7])))
           + (((p[8] + p[9]) + (p[10] + p[11])) + ((p[12] + p[13]) + (p[14] + p[15])));
  rs += __shfl_xor(rs, 16, 64);
  rs += __shfl_xor(rs, 32, 64);
  lsum += rs;
  uint32_t w00 = cvtpk2bf(p[0], p[1]),   w01 = cvtpk2bf(p[2], p[3]);
  uint32_t w10 = cvtpk2bf(p[4], p[5]),   w11 = cvtpk2bf(p[6], p[7]);
  uint32_t w20 = cvtpk2bf(p[8], p[9]),   w21 = cvtpk2bf(p[10], p[11]);
  uint32_t w30 = cvtpk2bf(p[12], p[13]), w31 = cvtpk2bf(p[14], p[15]);
  asm volatile("v_permlane32_swap_b32 %0, %1" : "+v"(w00), "+v"(w10));
  asm volatile("v_permlane16_swap_b32 %0, %1" : "+v"(w00), "+v"(w10));
  asm volatile("v_permlane32_swap_b32 %0, %1" : "+v"(w01), "+v"(w11));
  asm volatile("v_permlane16_swap_b32 %0, %1" : "+v"(w01), "+v"(w11));
  asm volatile("v_permlane32_swap_b32 %0, %1" : "+v"(w20), "+v"(w30));
  asm volatile("v_permlane16_swap_b32 %0, %1" : "+v"(w20), "+v"(w30));
  asm volatile("v_permlane32_swap_b32 %0, %1" : "+v"(w21), "+v"(w31));
  asm volatile("v_permlane16_swap_b32 %0, %1" : "+v"(w21), "+v"(w31));
  pq0[0] = w00; pq0[1] = w01; pq0[2] = w10; pq0[3] = w11;
  pq1[0] = w20; pq1[1] = w21; pq1[2] = w30; pq1[3] = w31;
}

// ---------------- flash attention: 512 threads, 8 waves x 32 q-rows ----------------
// grid (S/256, NQ, B); KVBLK=64; HD=64. launch_bounds(512,4): VGPR cap 128 (R9's spill
// was the (256,4) cap of 64). One K/V dbuf (64KB) feeds 256 q-rows/block: staging is
// 1 gld_lds per operand per wave per tile; K/V fetch drops ~4x.
__global__ __launch_bounds__(512, 4) void k_attn(const u16* __restrict__ QKV,
                                                 const u16* __restrict__ VT,
                                                 u16* __restrict__ Oa) {
  constexpr int S = 2048, LDQ = 3072;
  __shared__ __align__(16) u16 Ks[2][64 * 64];   // [key][d], chunk ^= row&7
  __shared__ __align__(16) u16 Vs[2][64 * 64];   // [d][key], chunk ^= row&7
  const int qt = blockIdx.x, h = blockIdx.y, b = blockIdx.z;
  const int kvh = h >> 2;
  const int tid = threadIdx.x, l = tid & 63, w = tid >> 6;   // w = 0..7
  const int lr = l & 15, lo = l >> 4;
  const size_t base = (size_t)b * S * LDQ;
  const u16* Qg = QKV + base + h * 64;
  const u16* Kg = QKV + base + 2048 + kvh * 64;
  const u16* Vg = VT + (size_t)(b * 8 + kvh) * 64 * 2048;
  const int qrow0 = qt * 256 + w * 32 + lr;      // group0 q-row; group1 = +16
  const bf16x8 aq0 = *reinterpret_cast<const bf16x8*>(Qg + (size_t)qrow0 * LDQ + lo * 8);
  const bf16x8 aq1 = *reinterpret_cast<const bf16x8*>(Qg + (size_t)qrow0 * LDQ + 32 + lo * 8);
  const bf16x8 aq2 = *reinterpret_cast<const bf16x8*>(Qg + (size_t)(qrow0 + 16) * LDQ + lo * 8);
  const bf16x8 aq3 = *reinterpret_cast<const bf16x8*>(Qg + (size_t)(qrow0 + 16) * LDQ + 32 + lo * 8);
  f32x4 acc0[4] = {}, acc1[4] = {};
  float mrun0 = -1e30f, lsum0 = 0.f, mrun1 = -1e30f, lsum1 = 0.f;
  const int krow = tid >> 3;                     // w*8 + (l>>3): rows 0..63 across 8 waves
  const int ksc = (l & 7) ^ ((l >> 3) & 7);
  // ---- prologue: stage tile 0 (1 issue per operand covers all 64 rows) ----
  gld_lds16(Kg + (size_t)krow * LDQ + ksc * 8, (char*)Ks[0] + (w * 8) * 128);
  gld_lds16(Vg + (size_t)krow * 2048 + ksc * 8, (char*)Vs[0] + (w * 8) * 128);
  int cur = 0;
  for (int kt = 0; kt < S; kt += 64) {
    __syncthreads();   // implicit vmcnt(0): buf[cur] (K+V) ready
    if (kt + 64 < S) { // prefetch tile t+1; in flight across compute(t)
      const int nb = cur ^ 1, nk = kt + 64;
      gld_lds16(Kg + (size_t)(nk + krow) * LDQ + ksc * 8, (char*)Ks[nb] + (w * 8) * 128);
      gld_lds16(Vg + (size_t)krow * 2048 + nk + ksc * 8, (char*)Vs[nb] + (w * 8) * 128);
    }
    // QK^T swapped, both q-groups: p0/p1[t*4+r] = S[key=16t+4lo+r][q]
    float p0[16], p1[16];
    const u16* KsC = Ks[cur];
    __builtin_amdgcn_s_setprio(1);
#pragma unroll
    for (int t = 0; t < 4; ++t) {
      const int row = t * 16 + lr;
      bf16x8 k0 = *reinterpret_cast<const bf16x8*>((const char*)KsC + row * 128 + ((lo ^ (row & 7)) * 16));
      bf16x8 k1 = *reinterpret_cast<const bf16x8*>((const char*)KsC + row * 128 + (((4 + lo) ^ (row & 7)) * 16));
      f32x4 z0 = {}, z1 = {};
      z0 = __builtin_amdgcn_mfma_f32_16x16x32_bf16(k0, aq0, z0, 0, 0, 0);
      z0 = __builtin_amdgcn_mfma_f32_16x16x32_bf16(k1, aq1, z0, 0, 0, 0);
      z1 = __builtin_amdgcn_mfma_f32_16x16x32_bf16(k0, aq2, z1, 0, 0, 0);
      z1 = __builtin_amdgcn_mfma_f32_16x16x32_bf16(k1, aq3, z1, 0, 0, 0);
#pragma unroll
      for (int r = 0; r < 4; ++r) { p0[t * 4 + r] = z0[r]; p1[t * 4 + r] = z1[r]; }
    }
    __builtin_amdgcn_s_setprio(0);
    u32x4 pq0, pq1, pq2, pq3;
    softmax_pack(p0, mrun0, lsum0, acc0, lo, pq0, pq1);
    softmax_pack(p1, mrun1, lsum1, acc1, lo, pq2, pq3);
    const bf16x8 pa0 = __builtin_bit_cast(bf16x8, pq0);
    const bf16x8 pa1 = __builtin_bit_cast(bf16x8, pq1);
    const bf16x8 pa2 = __builtin_bit_cast(bf16x8, pq2);
    const bf16x8 pa3 = __builtin_bit_cast(bf16x8, pq3);
    const u16* VsC = Vs[cur];
    __builtin_amdgcn_s_setprio(1);
#pragma unroll
    for (int nj = 0; nj < 4; ++nj) {
      const int vr = nj * 16 + lr;   // d row
      const bf16x8 bv0 = *reinterpret_cast<const bf16x8*>((const char*)VsC + vr * 128 + ((lo ^ (vr & 7)) * 16));
      const bf16x8 bv1 = *reinterpret_cast<const bf16x8*>((const char*)VsC + vr * 128 + (((4 + lo) ^ (vr & 7)) * 16));
      acc0[nj] = __builtin_amdgcn_mfma_f32_16x16x32_bf16(pa0, bv0, acc0[nj], 0, 0, 0);
      acc0[nj] = __builtin_amdgcn_mfma_f32_16x16x32_bf16(pa1, bv1, acc0[nj], 0, 0, 0);
      acc1[nj] = __builtin_amdgcn_mfma_f32_16x16x32_bf16(pa2, bv0, acc1[nj], 0, 0, 0);
      acc1[nj] = __builtin_amdgcn_mfma_f32_16x16x32_bf16(pa3, bv1, acc1[nj], 0, 0, 0);
    }
    __builtin_amdgcn_s_setprio(0);
    cur ^= 1;
  }
  float lf0[4], lf1[4];
#pragma unroll
  for (int r = 0; r < 4; ++r) {
    lf0[r] = 1.0f / __shfl(lsum0, lo * 4 + r, 64);
    lf1[r] = 1.0f / __shfl(lsum1, lo * 4 + r, 64);
  }
  const size_t orow0 = (size_t)b * S + qt * 256 + w * 32 + lo * 4;
#pragma unroll
  for (int nj = 0; nj < 4; ++nj) {
    const int col = h * 64 + nj * 16 + lr;
#pragma unroll
    for (int r = 0; r < 4; ++r) {
      Oa[(orow0 + r) * 2048 + col] = f2bf(acc0[nj][r] * lf0[r]);
      Oa[(orow0 + 16 + r) * 2048 + col] = f2bf(acc1[nj][r] * lf1[r]);
    }
  }
}

// ---------------- host ----------------
extern "C" void kernel_launch(void* const* d_in, const int* in_sizes, int n_in,
                              void* d_out, int out_size, void* d_ws, size_t ws_size,
                              hipStream_t stream) {
  const float* x  = (const float*)d_in[0];
  const float* Wq = (const float*)d_in[1];
  const float* bq = (const float*)d_in[2];
  const float* Wk = (const float*)d_in[3];
  const float* bk = (const float*)d_in[4];
  const float* Wv = (const float*)d_in[5];
  const float* bv = (const float*)d_in[6];
  const float* Wo = (const float*)d_in[7];
  const float* bo = (const float*)d_in[8];
  float* out = (float*)d_out;
  char* ws = (char*)d_ws;

  u16*   xb    = (u16*)(ws + 0);           // [4096][2048] bf16   16.78 MB (dead after QKV GEMM)
  u16*   vtg   = (u16*)(ws + 0);           // [2][8][64][2048] bf16 4 MB — aliases xb (written after GEMM)
  u16*   wqkvT = (u16*)(ws + 16777216);    // [3072][2048] bf16   12.58 MB
  u16*   woT   = (u16*)(ws + 29360128);    // [2048][2048] bf16    8.39 MB
  u16*   qkv   = (u16*)(ws + 37748736);    // [4096][3072] bf16   25.17 MB
  u16*   attn  = (u16*)(ws + 62914560);    // [4096][2048] bf16   16.78 MB

  const float SCL = 0.125f * 1.44269504088896341f;  // 1/sqrt(64) * log2(e)

  k_cast<<<4096, 256, 0, stream>>>(x, xb, 1048576);
  k_transpose_all<<<dim3(32, 32, 4), 256, 0, stream>>>(Wq, Wk, Wv, Wo, wqkvT, woT);
  k_gemm<false><<<dim3(24, 32), 256, 0, stream>>>(xb, wqkvT, bq, bk, bv, qkv,
                                                  4096, 3072, 2048, 2048, 2560, 2048, SCL);
  k_transpose_v<<<dim3(32, 8, 2), 256, 0, stream>>>(qkv, vtg);
  k_attn<<<dim3(8, 32, 2), 512, 0, stream>>>(qkv, vtg, attn);
  k_gemm<true><<<dim3(16, 32), 256, 0, stream>>>(attn, woT, bo, bo, bo, out,
                                                 4096, 2048, 2048, 2048, 4096, 0, 1.0f);
}

// Round 12
// 287.973 us; speedup vs baseline: 1.0568x; 1.0027x over previous
//
#include <hip/hip_runtime.h>
#include <cstdint>
#include <cstddef>

typedef unsigned short u16;
typedef __bf16 bf16x8 __attribute__((ext_vector_type(8)));
typedef float f32x4 __attribute__((ext_vector_type(4)));
typedef unsigned short u16x4 __attribute__((ext_vector_type(4)));
typedef unsigned short u16x8 __attribute__((ext_vector_type(8)));
typedef uint32_t u32x4 __attribute__((ext_vector_type(4)));
typedef __attribute__((address_space(1))) unsigned int as1_uint;
typedef __attribute__((address_space(3))) unsigned int as3_uint;

__device__ __forceinline__ u16 f2bf(float f) {
  uint32_t u = __builtin_bit_cast(uint32_t, f);
  u += 0x7FFFu + ((u >> 16) & 1u);   // RNE to bf16
  return (u16)(u >> 16);
}

// one-instruction packed f32x2 -> bf16x2 (RNE), T12 recipe
__device__ __forceinline__ uint32_t cvtpk2bf(float a, float b) {
  uint32_t r;
  asm("v_cvt_pk_bf16_f32 %0, %1, %2" : "=v"(r) : "v"(a), "v"(b));
  return r;
}

__device__ __forceinline__ float max3f(float a, float b, float c) {
  return fmaxf(fmaxf(a, b), c);   // clang fuses to v_max3_f32
}

__device__ __forceinline__ void gld_lds16(const void* g, void* l) {
  __builtin_amdgcn_global_load_lds((as1_uint*)g, (as3_uint*)l, 16, 0, 0);
}

// ---------------- cast fp32 -> bf16, 8 elems/thread ----------------
__global__ __launch_bounds__(256) void k_cast(const float* __restrict__ in,
                                              u16* __restrict__ out, int n8) {
  int i = blockIdx.x * 256 + threadIdx.x;
  if (i >= n8) return;
  const float4* p = reinterpret_cast<const float4*>(in) + (size_t)i * 2;
  float4 a = p[0], b = p[1];
  u16x8 r;
  r[0] = f2bf(a.x); r[1] = f2bf(a.y); r[2] = f2bf(a.z); r[3] = f2bf(a.w);
  r[4] = f2bf(b.x); r[5] = f2bf(b.y); r[6] = f2bf(b.z); r[7] = f2bf(b.w);
  *reinterpret_cast<u16x8*>(out + (size_t)i * 8) = r;
}

// ---------------- all 4 weight transposes in one launch ----------------
__global__ __launch_bounds__(256) void k_transpose_all(const float* __restrict__ Wq,
                                                       const float* __restrict__ Wk,
                                                       const float* __restrict__ Wv,
                                                       const float* __restrict__ Wo,
                                                       u16* __restrict__ wqkvT,
                                                       u16* __restrict__ woT) {
  constexpr int K = 2048;
  const int z = blockIdx.z;
  const float* W; u16* Wt; int N;
  if (z == 0)      { W = Wq; Wt = wqkvT;                        N = 2048; }
  else if (z == 1) { W = Wo; Wt = woT;                          N = 2048; }
  else if (z == 2) { W = Wk; Wt = wqkvT + (size_t)2048 * 2048;  N = 512;  }
  else             { W = Wv; Wt = wqkvT + (size_t)2560 * 2048;  N = 512;  }
  const int n0 = blockIdx.x * 64;
  if (n0 >= N) return;
  __shared__ u16 tile[64][72];
  const int k0 = blockIdx.y * 64;
  const int r = threadIdx.x >> 4;
  const int c4 = (threadIdx.x & 15) * 4;
#pragma unroll
  for (int i = 0; i < 4; ++i) {
    int kk = r + i * 16;
    float4 v = *reinterpret_cast<const float4*>(W + (size_t)(k0 + kk) * N + n0 + c4);
    tile[kk][c4 + 0] = f2bf(v.x); tile[kk][c4 + 1] = f2bf(v.y);
    tile[kk][c4 + 2] = f2bf(v.z); tile[kk][c4 + 3] = f2bf(v.w);
  }
  __syncthreads();
#pragma unroll
  for (int i = 0; i < 4; ++i) {
    int nn = r + i * 16;
    u16x4 o;
    o[0] = tile[c4 + 0][nn]; o[1] = tile[c4 + 1][nn];
    o[2] = tile[c4 + 2][nn]; o[3] = tile[c4 + 3][nn];
    *reinterpret_cast<u16x4*>(Wt + (size_t)(n0 + nn) * K + k0 + c4) = o;
  }
}

// ---------------- V-part of qkv -> Vt_g[b][kvh][d][token] ----------------
__global__ __launch_bounds__(256) void k_transpose_v(const u16* __restrict__ qkv,
                                                     u16* __restrict__ vt) {
  __shared__ u16 tile[64][72];
  const int t0 = blockIdx.x * 64, kvh = blockIdx.y, b = blockIdx.z;
  const u16* src = qkv + ((size_t)(b * 2048) + t0) * 3072 + 2560 + kvh * 64;
  u16* dst = vt + ((size_t)(b * 8 + kvh) * 64) * 2048 + t0;
  const int r = threadIdx.x >> 3;          // 0..31
  const int c8 = (threadIdx.x & 7) * 8;    // 0..56
#pragma unroll
  for (int i = 0; i < 2; ++i) {
    int rr = r + i * 32;                   // token row
    u16x8 v = *reinterpret_cast<const u16x8*>(src + (size_t)rr * 3072 + c8);
#pragma unroll
    for (int j = 0; j < 8; ++j) tile[c8 + j][rr] = v[j];
  }
  __syncthreads();
#pragma unroll
  for (int i = 0; i < 2; ++i) {
    int rr = r + i * 32;                   // d row
    u16x8 o;
#pragma unroll
    for (int j = 0; j < 8; ++j) o[j] = tile[rr][c8 + j];
    *reinterpret_cast<u16x8*>(dst + (size_t)rr * 2048 + c8) = o;
  }
}

// ---------------- bf16 GEMM: C = (A @ Bt^T + bias(col)) * colscale ----------------
// 128x128 tile, BK=64, 4 waves (2x2), 16x16x32 MFMA; T1 bijective XCD swizzle (nwg%8==0).
template <bool F32OUT>
__global__ __launch_bounds__(256) void k_gemm(const u16* __restrict__ A,
                                              const u16* __restrict__ Bt,
                                              const float* __restrict__ b0,
                                              const float* __restrict__ b1,
                                              const float* __restrict__ b2,
                                              void* __restrict__ Cout,
                                              int M, int N, int K,
                                              int n1, int n2,
                                              int scaleN, float scaleV) {
  __shared__ __align__(16) u16 As[128 * 64];
  __shared__ __align__(16) u16 Bs[128 * 64];
  const int id = blockIdx.y * gridDim.x + blockIdx.x;
  const int cpx = (gridDim.x * gridDim.y) >> 3;
  const int nid = (id & 7) * cpx + (id >> 3);
  const int m0 = (nid / gridDim.x) * 128, n0 = (nid % gridDim.x) * 128;
  const int tid = threadIdx.x;
  const int l = tid & 63, w = tid >> 6;
  const int wm = w >> 1, wn = w & 1;
  const int lr = l & 15, lo = l >> 4;
  const int srow = w * 8 + (l >> 3);
  const int sc = (l & 7) ^ ((l >> 3) & 7);
  f32x4 acc[4][4] = {};
  for (int kt = 0; kt < K; kt += 64) {
    __syncthreads();
#pragma unroll
    for (int it = 0; it < 4; ++it) {
      int row = it * 32 + srow;
      gld_lds16(A + (size_t)(m0 + row) * K + kt + sc * 8,
                (char*)As + (it * 32 + w * 8) * 128);
      gld_lds16(Bt + (size_t)(n0 + row) * K + kt + sc * 8,
                (char*)Bs + (it * 32 + w * 8) * 128);
    }
    __syncthreads();
    bf16x8 af[4][2], bfr[4][2];
#pragma unroll
    for (int mi = 0; mi < 4; ++mi) {
      int row = wm * 64 + mi * 16 + lr;
#pragma unroll
      for (int ks = 0; ks < 2; ++ks) {
        int ch = (ks * 4 + lo) ^ (row & 7);
        af[mi][ks] = *reinterpret_cast<const bf16x8*>((const char*)As + row * 128 + ch * 16);
      }
    }
#pragma unroll
    for (int nj = 0; nj < 4; ++nj) {
      int row = wn * 64 + nj * 16 + lr;
#pragma unroll
      for (int ks = 0; ks < 2; ++ks) {
        int ch = (ks * 4 + lo) ^ (row & 7);
        bfr[nj][ks] = *reinterpret_cast<const bf16x8*>((const char*)Bs + row * 128 + ch * 16);
      }
    }
#pragma unroll
    for (int mi = 0; mi < 4; ++mi)
#pragma unroll
      for (int nj = 0; nj < 4; ++nj) {
        acc[mi][nj] = __builtin_amdgcn_mfma_f32_16x16x32_bf16(af[mi][0], bfr[nj][0], acc[mi][nj], 0, 0, 0);
        acc[mi][nj] = __builtin_amdgcn_mfma_f32_16x16x32_bf16(af[mi][1], bfr[nj][1], acc[mi][nj], 0, 0, 0);
      }
  }
#pragma unroll
  for (int mi = 0; mi < 4; ++mi) {
    int row = m0 + wm * 64 + mi * 16 + lo * 4;
#pragma unroll
    for (int nj = 0; nj < 4; ++nj) {
      int col = n0 + wn * 64 + nj * 16 + lr;
      float bv = (col < n1) ? b0[col] : (col < n2 ? b1[col - n1] : b2[col - n2]);
      float scc = (col < scaleN) ? scaleV : 1.0f;
#pragma unroll
      for (int r = 0; r < 4; ++r) {
        float v = (acc[mi][nj][r] + bv) * scc;
        if (F32OUT) ((float*)Cout)[(size_t)(row + r) * N + col] = v;
        else        ((u16*)Cout)[(size_t)(row + r) * N + col] = f2bf(v);
      }
    }
  }
}

// online-softmax one 16-q group -> PA frags + state (verified R8/R10 math)
__device__ __forceinline__ void softmax_pack(float (&p)[16], float& mrun, float& lsum,
                                             f32x4 (&acc)[4], int lo,
                                             u32x4& pq0, u32x4& pq1) {
  constexpr float THR = 8.0f;
  float m0 = max3f(p[0], p[1], p[2]);
  float m1 = max3f(p[3], p[4], p[5]);
  float m2 = max3f(p[6], p[7], p[8]);
  float m3 = max3f(p[9], p[10], p[11]);
  float m4 = max3f(p[12], p[13], p[14]);
  float tm = fmaxf(max3f(m0, m1, m2), max3f(m3, m4, p[15]));
  tm = fmaxf(tm, __shfl_xor(tm, 16, 64));
  tm = fmaxf(tm, __shfl_xor(tm, 32, 64));
  if (__all(tm <= mrun + THR)) {
#pragma unroll
    for (int i = 0; i < 16; ++i) p[i] = __builtin_amdgcn_exp2f(p[i] - mrun);
  } else {
    float mnew = fmaxf(mrun, tm);
    float alpha = __builtin_amdgcn_exp2f(mrun - mnew);
    mrun = mnew;
#pragma unroll
    for (int i = 0; i < 16; ++i) p[i] = __builtin_amdgcn_exp2f(p[i] - mnew);
    lsum *= alpha;
#pragma unroll
    for (int r = 0; r < 4; ++r) {
      float ar = __shfl(alpha, lo * 4 + r, 64);
#pragma unroll
      for (int nj = 0; nj < 4; ++nj) acc[nj][r] *= ar;
    }
  }
  float rs = (((p[0] + p[1]) + (p[2] + p[3])) + ((p[4] + p[5]) + (p[6] + p[7])))
           + (((p[8] + p[9]) + (p[10] + p[11])) + ((p[12] + p[13]) + (p[14] + p[15])));
  rs += __shfl_xor(rs, 16, 64);
  rs += __shfl_xor(rs, 32, 64);
  lsum += rs;
  uint32_t w00 = cvtpk2bf(p[0], p[1]),   w01 = cvtpk2bf(p[2], p[3]);
  uint32_t w10 = cvtpk2bf(p[4], p[5]),   w11 = cvtpk2bf(p[6], p[7]);
  uint32_t w20 = cvtpk2bf(p[8], p[9]),   w21 = cvtpk2bf(p[10], p[11]);
  uint32_t w30 = cvtpk2bf(p[12], p[13]), w31 = cvtpk2bf(p[14], p[15]);
  asm volatile("v_permlane32_swap_b32 %0, %1" : "+v"(w00), "+v"(w10));
  asm volatile("v_permlane16_swap_b32 %0, %1" : "+v"(w00), "+v"(w10));
  asm volatile("v_permlane32_swap_b32 %0, %1" : "+v"(w01), "+v"(w11));
  asm volatile("v_permlane16_swap_b32 %0, %1" : "+v"(w01), "+v"(w11));
  asm volatile("v_permlane32_swap_b32 %0, %1" : "+v"(w20), "+v"(w30));
  asm volatile("v_permlane16_swap_b32 %0, %1" : "+v"(w20), "+v"(w30));
  asm volatile("v_permlane32_swap_b32 %0, %1" : "+v"(w21), "+v"(w31));
  asm volatile("v_permlane16_swap_b32 %0, %1" : "+v"(w21), "+v"(w31));
  pq0[0] = w00; pq0[1] = w01; pq0[2] = w10; pq0[3] = w11;
  pq1[0] = w20; pq1[1] = w21; pq1[2] = w30; pq1[3] = w31;
}

// ---------------- flash attention: 512 threads, 8 waves x 32 q-rows ----------------
// grid (S/256, NQ, B); KVBLK=64; HD=64. launch_bounds(512,2): waves/EU=2 -> VGPR cap 128
// (cap = 256/waves_per_EU regardless of block size; R11's (512,4) capped at 64 -> spill).
// 2 blocks/CU (LDS 2x64KB=128<=160KB), VGPR~110 allows 4 waves/SIMD = 16 waves/CU.
__global__ __launch_bounds__(512, 2) void k_attn(const u16* __restrict__ QKV,
                                                 const u16* __restrict__ VT,
                                                 u16* __restrict__ Oa) {
  constexpr int S = 2048, LDQ = 3072;
  __shared__ __align__(16) u16 Ks[2][64 * 64];   // [key][d], chunk ^= row&7
  __shared__ __align__(16) u16 Vs[2][64 * 64];   // [d][key], chunk ^= row&7
  const int qt = blockIdx.x, h = blockIdx.y, b = blockIdx.z;
  const int kvh = h >> 2;
  const int tid = threadIdx.x, l = tid & 63, w = tid >> 6;   // w = 0..7
  const int lr = l & 15, lo = l >> 4;
  const size_t base = (size_t)b * S * LDQ;
  const u16* Qg = QKV + base + h * 64;
  const u16* Kg = QKV + base + 2048 + kvh * 64;
  const u16* Vg = VT + (size_t)(b * 8 + kvh) * 64 * 2048;
  const int qrow0 = qt * 256 + w * 32 + lr;      // group0 q-row; group1 = +16
  const bf16x8 aq0 = *reinterpret_cast<const bf16x8*>(Qg + (size_t)qrow0 * LDQ + lo * 8);
  const bf16x8 aq1 = *reinterpret_cast<const bf16x8*>(Qg + (size_t)qrow0 * LDQ + 32 + lo * 8);
  const bf16x8 aq2 = *reinterpret_cast<const bf16x8*>(Qg + (size_t)(qrow0 + 16) * LDQ + lo * 8);
  const bf16x8 aq3 = *reinterpret_cast<const bf16x8*>(Qg + (size_t)(qrow0 + 16) * LDQ + 32 + lo * 8);
  f32x4 acc0[4] = {}, acc1[4] = {};
  float mrun0 = -1e30f, lsum0 = 0.f, mrun1 = -1e30f, lsum1 = 0.f;
  const int krow = tid >> 3;                     // rows 0..63 across 8 waves
  const int ksc = (l & 7) ^ ((l >> 3) & 7);
  // ---- prologue: stage tile 0 (1 issue per operand covers all 64 rows) ----
  gld_lds16(Kg + (size_t)krow * LDQ + ksc * 8, (char*)Ks[0] + (w * 8) * 128);
  gld_lds16(Vg + (size_t)krow * 2048 + ksc * 8, (char*)Vs[0] + (w * 8) * 128);
  int cur = 0;
  for (int kt = 0; kt < S; kt += 64) {
    __syncthreads();   // implicit vmcnt(0): buf[cur] (K+V) ready
    if (kt + 64 < S) { // prefetch tile t+1; in flight across compute(t)
      const int nb = cur ^ 1, nk = kt + 64;
      gld_lds16(Kg + (size_t)(nk + krow) * LDQ + ksc * 8, (char*)Ks[nb] + (w * 8) * 128);
      gld_lds16(Vg + (size_t)krow * 2048 + nk + ksc * 8, (char*)Vs[nb] + (w * 8) * 128);
    }
    // QK^T swapped, both q-groups: p0/p1[t*4+r] = S[key=16t+4lo+r][q]
    float p0[16], p1[16];
    const u16* KsC = Ks[cur];
    __builtin_amdgcn_s_setprio(1);
#pragma unroll
    for (int t = 0; t < 4; ++t) {
      const int row = t * 16 + lr;
      bf16x8 k0 = *reinterpret_cast<const bf16x8*>((const char*)KsC + row * 128 + ((lo ^ (row & 7)) * 16));
      bf16x8 k1 = *reinterpret_cast<const bf16x8*>((const char*)KsC + row * 128 + (((4 + lo) ^ (row & 7)) * 16));
      f32x4 z0 = {}, z1 = {};
      z0 = __builtin_amdgcn_mfma_f32_16x16x32_bf16(k0, aq0, z0, 0, 0, 0);
      z0 = __builtin_amdgcn_mfma_f32_16x16x32_bf16(k1, aq1, z0, 0, 0, 0);
      z1 = __builtin_amdgcn_mfma_f32_16x16x32_bf16(k0, aq2, z1, 0, 0, 0);
      z1 = __builtin_amdgcn_mfma_f32_16x16x32_bf16(k1, aq3, z1, 0, 0, 0);
#pragma unroll
      for (int r = 0; r < 4; ++r) { p0[t * 4 + r] = z0[r]; p1[t * 4 + r] = z1[r]; }
    }
    __builtin_amdgcn_s_setprio(0);
    u32x4 pq0, pq1, pq2, pq3;
    softmax_pack(p0, mrun0, lsum0, acc0, lo, pq0, pq1);
    softmax_pack(p1, mrun1, lsum1, acc1, lo, pq2, pq3);
    const bf16x8 pa0 = __builtin_bit_cast(bf16x8, pq0);
    const bf16x8 pa1 = __builtin_bit_cast(bf16x8, pq1);
    const bf16x8 pa2 = __builtin_bit_cast(bf16x8, pq2);
    const bf16x8 pa3 = __builtin_bit_cast(bf16x8, pq3);
    const u16* VsC = Vs[cur];
    __builtin_amdgcn_s_setprio(1);
#pragma unroll
    for (int nj = 0; nj < 4; ++nj) {
      const int vr = nj * 16 + lr;   // d row
      const bf16x8 bv0 = *reinterpret_cast<const bf16x8*>((const char*)VsC + vr * 128 + ((lo ^ (vr & 7)) * 16));
      const bf16x8 bv1 = *reinterpret_cast<const bf16x8*>((const char*)VsC + vr * 128 + (((4 + lo) ^ (vr & 7)) * 16));
      acc0[nj] = __builtin_amdgcn_mfma_f32_16x16x32_bf16(pa0, bv0, acc0[nj], 0, 0, 0);
      acc0[nj] = __builtin_amdgcn_mfma_f32_16x16x32_bf16(pa1, bv1, acc0[nj], 0, 0, 0);
      acc1[nj] = __builtin_amdgcn_mfma_f32_16x16x32_bf16(pa2, bv0, acc1[nj], 0, 0, 0);
      acc1[nj] = __builtin_amdgcn_mfma_f32_16x16x32_bf16(pa3, bv1, acc1[nj], 0, 0, 0);
    }
    __builtin_amdgcn_s_setprio(0);
    cur ^= 1;
  }
  float lf0[4], lf1[4];
#pragma unroll
  for (int r = 0; r < 4; ++r) {
    lf0[r] = 1.0f / __shfl(lsum0, lo * 4 + r, 64);
    lf1[r] = 1.0f / __shfl(lsum1, lo * 4 + r, 64);
  }
  const size_t orow0 = (size_t)b * S + qt * 256 + w * 32 + lo * 4;
#pragma unroll
  for (int nj = 0; nj < 4; ++nj) {
    const int col = h * 64 + nj * 16 + lr;
#pragma unroll
    for (int r = 0; r < 4; ++r) {
      Oa[(orow0 + r) * 2048 + col] = f2bf(acc0[nj][r] * lf0[r]);
      Oa[(orow0 + 16 + r) * 2048 + col] = f2bf(acc1[nj][r] * lf1[r]);
    }
  }
}

// ---------------- host ----------------
extern "C" void kernel_launch(void* const* d_in, const int* in_sizes, int n_in,
                              void* d_out, int out_size, void* d_ws, size_t ws_size,
                              hipStream_t stream) {
  const float* x  = (const float*)d_in[0];
  const float* Wq = (const float*)d_in[1];
  const float* bq = (const float*)d_in[2];
  const float* Wk = (const float*)d_in[3];
  const float* bk = (const float*)d_in[4];
  const float* Wv = (const float*)d_in[5];
  const float* bv = (const float*)d_in[6];
  const float* Wo = (const float*)d_in[7];
  const float* bo = (const float*)d_in[8];
  float* out = (float*)d_out;
  char* ws = (char*)d_ws;

  u16*   xb    = (u16*)(ws + 0);           // [4096][2048] bf16   16.78 MB (dead after QKV GEMM)
  u16*   vtg   = (u16*)(ws + 0);           // [2][8][64][2048] bf16 4 MB — aliases xb (written after GEMM)
  u16*   wqkvT = (u16*)(ws + 16777216);    // [3072][2048] bf16   12.58 MB
  u16*   woT   = (u16*)(ws + 29360128);    // [2048][2048] bf16    8.39 MB
  u16*   qkv   = (u16*)(ws + 37748736);    // [4096][3072] bf16   25.17 MB
  u16*   attn  = (u16*)(ws + 62914560);    // [4096][2048] bf16   16.78 MB

  const float SCL = 0.125f * 1.44269504088896341f;  // 1/sqrt(64) * log2(e)

  k_cast<<<4096, 256, 0, stream>>>(x, xb, 1048576);
  k_transpose_all<<<dim3(32, 32, 4), 256, 0, stream>>>(Wq, Wk, Wv, Wo, wqkvT, woT);
  k_gemm<false><<<dim3(24, 32), 256, 0, stream>>>(xb, wqkvT, bq, bk, bv, qkv,
                                                  4096, 3072, 2048, 2048, 2560, 2048, SCL);
  k_transpose_v<<<dim3(32, 8, 2), 256, 0, stream>>>(qkv, vtg);
  k_attn<<<dim3(8, 32, 2), 512, 0, stream>>>(qkv, vtg, attn);
  k_gemm<true><<<dim3(16, 32), 256, 0, stream>>>(attn, woT, bo, bo, bo, out,
                                                 4096, 2048, 2048, 2048, 4096, 0, 1.0f);
}

// Round 13
// 286.057 us; speedup vs baseline: 1.0639x; 1.0067x over previous
//
#include <hip/hip_runtime.h>
#include <cstdint>
#include <cstddef>

typedef unsigned short u16;
typedef __bf16 bf16x8 __attribute__((ext_vector_type(8)));
typedef float f32x4 __attribute__((ext_vector_type(4)));
typedef unsigned short u16x4 __attribute__((ext_vector_type(4)));
typedef unsigned short u16x8 __attribute__((ext_vector_type(8)));
typedef uint32_t u32x4 __attribute__((ext_vector_type(4)));
typedef __attribute__((address_space(1))) unsigned int as1_uint;
typedef __attribute__((address_space(3))) unsigned int as3_uint;

__device__ __forceinline__ u16 f2bf(float f) {
  uint32_t u = __builtin_bit_cast(uint32_t, f);
  u += 0x7FFFu + ((u >> 16) & 1u);   // RNE to bf16
  return (u16)(u >> 16);
}

// one-instruction packed f32x2 -> bf16x2 (RNE), T12 recipe
__device__ __forceinline__ uint32_t cvtpk2bf(float a, float b) {
  uint32_t r;
  asm("v_cvt_pk_bf16_f32 %0, %1, %2" : "=v"(r) : "v"(a), "v"(b));
  return r;
}

__device__ __forceinline__ float max3f(float a, float b, float c) {
  return fmaxf(fmaxf(a, b), c);   // clang fuses to v_max3_f32
}

__device__ __forceinline__ void gld_lds16(const void* g, void* l) {
  __builtin_amdgcn_global_load_lds((as1_uint*)g, (as3_uint*)l, 16, 0, 0);
}

// ---------------- cast fp32 -> bf16, 8 elems/thread ----------------
__global__ __launch_bounds__(256) void k_cast(const float* __restrict__ in,
                                              u16* __restrict__ out, int n8) {
  int i = blockIdx.x * 256 + threadIdx.x;
  if (i >= n8) return;
  const float4* p = reinterpret_cast<const float4*>(in) + (size_t)i * 2;
  float4 a = p[0], b = p[1];
  u16x8 r;
  r[0] = f2bf(a.x); r[1] = f2bf(a.y); r[2] = f2bf(a.z); r[3] = f2bf(a.w);
  r[4] = f2bf(b.x); r[5] = f2bf(b.y); r[6] = f2bf(b.z); r[7] = f2bf(b.w);
  *reinterpret_cast<u16x8*>(out + (size_t)i * 8) = r;
}

// ---------------- all 4 weight transposes in one launch ----------------
__global__ __launch_bounds__(256) void k_transpose_all(const float* __restrict__ Wq,
                                                       const float* __restrict__ Wk,
                                                       const float* __restrict__ Wv,
                                                       const float* __restrict__ Wo,
                                                       u16* __restrict__ wqkvT,
                                                       u16* __restrict__ woT) {
  constexpr int K = 2048;
  const int z = blockIdx.z;
  const float* W; u16* Wt; int N;
  if (z == 0)      { W = Wq; Wt = wqkvT;                        N = 2048; }
  else if (z == 1) { W = Wo; Wt = woT;                          N = 2048; }
  else if (z == 2) { W = Wk; Wt = wqkvT + (size_t)2048 * 2048;  N = 512;  }
  else             { W = Wv; Wt = wqkvT + (size_t)2560 * 2048;  N = 512;  }
  const int n0 = blockIdx.x * 64;
  if (n0 >= N) return;
  __shared__ u16 tile[64][72];
  const int k0 = blockIdx.y * 64;
  const int r = threadIdx.x >> 4;
  const int c4 = (threadIdx.x & 15) * 4;
#pragma unroll
  for (int i = 0; i < 4; ++i) {
    int kk = r + i * 16;
    float4 v = *reinterpret_cast<const float4*>(W + (size_t)(k0 + kk) * N + n0 + c4);
    tile[kk][c4 + 0] = f2bf(v.x); tile[kk][c4 + 1] = f2bf(v.y);
    tile[kk][c4 + 2] = f2bf(v.z); tile[kk][c4 + 3] = f2bf(v.w);
  }
  __syncthreads();
#pragma unroll
  for (int i = 0; i < 4; ++i) {
    int nn = r + i * 16;
    u16x4 o;
    o[0] = tile[c4 + 0][nn]; o[1] = tile[c4 + 1][nn];
    o[2] = tile[c4 + 2][nn]; o[3] = tile[c4 + 3][nn];
    *reinterpret_cast<u16x4*>(Wt + (size_t)(n0 + nn) * K + k0 + c4) = o;
  }
}

// ---------------- V-part of qkv -> Vt_g[b][kvh][d][token] ----------------
__global__ __launch_bounds__(256) void k_transpose_v(const u16* __restrict__ qkv,
                                                     u16* __restrict__ vt) {
  __shared__ u16 tile[64][72];
  const int t0 = blockIdx.x * 64, kvh = blockIdx.y, b = blockIdx.z;
  const u16* src = qkv + ((size_t)(b * 2048) + t0) * 3072 + 2560 + kvh * 64;
  u16* dst = vt + ((size_t)(b * 8 + kvh) * 64) * 2048 + t0;
  const int r = threadIdx.x >> 3;          // 0..31
  const int c8 = (threadIdx.x & 7) * 8;    // 0..56
#pragma unroll
  for (int i = 0; i < 2; ++i) {
    int rr = r + i * 32;                   // token row
    u16x8 v = *reinterpret_cast<const u16x8*>(src + (size_t)rr * 3072 + c8);
#pragma unroll
    for (int j = 0; j < 8; ++j) tile[c8 + j][rr] = v[j];
  }
  __syncthreads();
#pragma unroll
  for (int i = 0; i < 2; ++i) {
    int rr = r + i * 32;                   // d row
    u16x8 o;
#pragma unroll
    for (int j = 0; j < 8; ++j) o[j] = tile[rr][c8 + j];
    *reinterpret_cast<u16x8*>(dst + (size_t)rr * 2048 + c8) = o;
  }
}

// ---------------- bf16 GEMM: C = (A @ Bt^T + bias(col)) * colscale ----------------
// 128x128 tile, BK=64, 4 waves (2x2), 16x16x32 MFMA; T1 bijective XCD swizzle (nwg%8==0).
template <bool F32OUT>
__global__ __launch_bounds__(256) void k_gemm(const u16* __restrict__ A,
                                              const u16* __restrict__ Bt,
                                              const float* __restrict__ b0,
                                              const float* __restrict__ b1,
                                              const float* __restrict__ b2,
                                              void* __restrict__ Cout,
                                              int M, int N, int K,
                                              int n1, int n2,
                                              int scaleN, float scaleV) {
  __shared__ __align__(16) u16 As[128 * 64];
  __shared__ __align__(16) u16 Bs[128 * 64];
  const int id = blockIdx.y * gridDim.x + blockIdx.x;
  const int cpx = (gridDim.x * gridDim.y) >> 3;
  const int nid = (id & 7) * cpx + (id >> 3);
  const int m0 = (nid / gridDim.x) * 128, n0 = (nid % gridDim.x) * 128;
  const int tid = threadIdx.x;
  const int l = tid & 63, w = tid >> 6;
  const int wm = w >> 1, wn = w & 1;
  const int lr = l & 15, lo = l >> 4;
  const int srow = w * 8 + (l >> 3);
  const int sc = (l & 7) ^ ((l >> 3) & 7);
  f32x4 acc[4][4] = {};
  for (int kt = 0; kt < K; kt += 64) {
    __syncthreads();
#pragma unroll
    for (int it = 0; it < 4; ++it) {
      int row = it * 32 + srow;
      gld_lds16(A + (size_t)(m0 + row) * K + kt + sc * 8,
                (char*)As + (it * 32 + w * 8) * 128);
      gld_lds16(Bt + (size_t)(n0 + row) * K + kt + sc * 8,
                (char*)Bs + (it * 32 + w * 8) * 128);
    }
    __syncthreads();
    bf16x8 af[4][2], bfr[4][2];
#pragma unroll
    for (int mi = 0; mi < 4; ++mi) {
      int row = wm * 64 + mi * 16 + lr;
#pragma unroll
      for (int ks = 0; ks < 2; ++ks) {
        int ch = (ks * 4 + lo) ^ (row & 7);
        af[mi][ks] = *reinterpret_cast<const bf16x8*>((const char*)As + row * 128 + ch * 16);
      }
    }
#pragma unroll
    for (int nj = 0; nj < 4; ++nj) {
      int row = wn * 64 + nj * 16 + lr;
#pragma unroll
      for (int ks = 0; ks < 2; ++ks) {
        int ch = (ks * 4 + lo) ^ (row & 7);
        bfr[nj][ks] = *reinterpret_cast<const bf16x8*>((const char*)Bs + row * 128 + ch * 16);
      }
    }
#pragma unroll
    for (int mi = 0; mi < 4; ++mi)
#pragma unroll
      for (int nj = 0; nj < 4; ++nj) {
        acc[mi][nj] = __builtin_amdgcn_mfma_f32_16x16x32_bf16(af[mi][0], bfr[nj][0], acc[mi][nj], 0, 0, 0);
        acc[mi][nj] = __builtin_amdgcn_mfma_f32_16x16x32_bf16(af[mi][1], bfr[nj][1], acc[mi][nj], 0, 0, 0);
      }
  }
#pragma unroll
  for (int mi = 0; mi < 4; ++mi) {
    int row = m0 + wm * 64 + mi * 16 + lo * 4;
#pragma unroll
    for (int nj = 0; nj < 4; ++nj) {
      int col = n0 + wn * 64 + nj * 16 + lr;
      float bv = (col < n1) ? b0[col] : (col < n2 ? b1[col - n1] : b2[col - n2]);
      float scc = (col < scaleN) ? scaleV : 1.0f;
#pragma unroll
      for (int r = 0; r < 4; ++r) {
        float v = (acc[mi][nj][r] + bv) * scc;
        if (F32OUT) ((float*)Cout)[(size_t)(row + r) * N + col] = v;
        else        ((u16*)Cout)[(size_t)(row + r) * N + col] = f2bf(v);
      }
    }
  }
}

// ---------------- flash attention: 512 threads, 8 waves x 16 q-rows ----------------
// grid (S/128, NQ, B); KVBLK=64; HD=64. launch_bounds(512,2).
// Single q-group per wave (R10 register budget ~52-56 VGPR -> 2 blocks/CU = 16 waves/CU)
// + 8-wave staging amortization (1 gld_lds issue per operand per wave per tile; R12's
// dual-group VGPR=76 allowed only 1 block/CU -> latency-exposed).
__global__ __launch_bounds__(512, 2) void k_attn(const u16* __restrict__ QKV,
                                                 const u16* __restrict__ VT,
                                                 u16* __restrict__ Oa) {
  constexpr int S = 2048, LDQ = 3072;
  constexpr float THR = 8.0f;
  __shared__ __align__(16) u16 Ks[2][64 * 64];   // [key][d], chunk ^= row&7
  __shared__ __align__(16) u16 Vs[2][64 * 64];   // [d][key], chunk ^= row&7
  const int qt = blockIdx.x, h = blockIdx.y, b = blockIdx.z;
  const int kvh = h >> 2;
  const int tid = threadIdx.x, l = tid & 63, w = tid >> 6;   // w = 0..7
  const int lr = l & 15, lo = l >> 4;
  const size_t base = (size_t)b * S * LDQ;
  const u16* Qg = QKV + base + h * 64;
  const u16* Kg = QKV + base + 2048 + kvh * 64;
  const u16* Vg = VT + (size_t)(b * 8 + kvh) * 64 * 2048;
  const int qrow = qt * 128 + w * 16 + lr;
  const bf16x8 aq0 = *reinterpret_cast<const bf16x8*>(Qg + (size_t)qrow * LDQ + lo * 8);
  const bf16x8 aq1 = *reinterpret_cast<const bf16x8*>(Qg + (size_t)qrow * LDQ + 32 + lo * 8);
  f32x4 acc[4] = {};
  float mrun = -1e30f, lsum = 0.f;
  const int krow = tid >> 3;                     // rows 0..63 across 8 waves
  const int ksc = (l & 7) ^ ((l >> 3) & 7);
  // ---- prologue: stage tile 0 (1 issue per operand covers all 64 rows) ----
  gld_lds16(Kg + (size_t)krow * LDQ + ksc * 8, (char*)Ks[0] + (w * 8) * 128);
  gld_lds16(Vg + (size_t)krow * 2048 + ksc * 8, (char*)Vs[0] + (w * 8) * 128);
  int cur = 0;
  for (int kt = 0; kt < S; kt += 64) {
    __syncthreads();   // implicit vmcnt(0): buf[cur] (K+V) ready
    if (kt + 64 < S) { // prefetch tile t+1; in flight across compute(t)
      const int nb = cur ^ 1, nk = kt + 64;
      gld_lds16(Kg + (size_t)(nk + krow) * LDQ + ksc * 8, (char*)Ks[nb] + (w * 8) * 128);
      gld_lds16(Vg + (size_t)krow * 2048 + nk + ksc * 8, (char*)Vs[nb] + (w * 8) * 128);
    }
    // QK^T swapped: p[t*4+r] = S[key=16t+4lo+r][q=lr]  (Q pre-scaled by log2e/sqrt(HD))
    float p[16];
    const u16* KsC = Ks[cur];
    __builtin_amdgcn_s_setprio(1);
#pragma unroll
    for (int t = 0; t < 4; ++t) {
      const int row = t * 16 + lr;
      bf16x8 k0 = *reinterpret_cast<const bf16x8*>((const char*)KsC + row * 128 + ((lo ^ (row & 7)) * 16));
      bf16x8 k1 = *reinterpret_cast<const bf16x8*>((const char*)KsC + row * 128 + (((4 + lo) ^ (row & 7)) * 16));
      f32x4 zz = {};
      zz = __builtin_amdgcn_mfma_f32_16x16x32_bf16(k0, aq0, zz, 0, 0, 0);
      zz = __builtin_amdgcn_mfma_f32_16x16x32_bf16(k1, aq1, zz, 0, 0, 0);
#pragma unroll
      for (int r = 0; r < 4; ++r) p[t * 4 + r] = zz[r];
    }
    __builtin_amdgcn_s_setprio(0);
    // tile max for q=lr: max3 tree + 2 shfl
    float m0 = max3f(p[0], p[1], p[2]);
    float m1 = max3f(p[3], p[4], p[5]);
    float m2 = max3f(p[6], p[7], p[8]);
    float m3 = max3f(p[9], p[10], p[11]);
    float m4 = max3f(p[12], p[13], p[14]);
    float tm = fmaxf(max3f(m0, m1, m2), max3f(m3, m4, p[15]));
    tm = fmaxf(tm, __shfl_xor(tm, 16, 64));
    tm = fmaxf(tm, __shfl_xor(tm, 32, 64));
    if (__all(tm <= mrun + THR)) {
      // defer-max: keep stale mrun; p bounded by 2^THR
#pragma unroll
      for (int i = 0; i < 16; ++i) p[i] = __builtin_amdgcn_exp2f(p[i] - mrun);
    } else {
      float mnew = fmaxf(mrun, tm);
      float alpha = __builtin_amdgcn_exp2f(mrun - mnew);
      mrun = mnew;
#pragma unroll
      for (int i = 0; i < 16; ++i) p[i] = __builtin_amdgcn_exp2f(p[i] - mnew);
      lsum *= alpha;
#pragma unroll
      for (int r = 0; r < 4; ++r) {
        float ar = __shfl(alpha, lo * 4 + r, 64);   // alpha for acc-row q=lo*4+r
#pragma unroll
        for (int nj = 0; nj < 4; ++nj) acc[nj][r] *= ar;
      }
    }
    float rs = (((p[0] + p[1]) + (p[2] + p[3])) + ((p[4] + p[5]) + (p[6] + p[7])))
             + (((p[8] + p[9]) + (p[10] + p[11])) + ((p[12] + p[13]) + (p[14] + p[15])));
    rs += __shfl_xor(rs, 16, 64);
    rs += __shfl_xor(rs, 32, 64);
    lsum += rs;
    // pack P pairs with v_cvt_pk_bf16_f32 (1 instr each)
    uint32_t w00 = cvtpk2bf(p[0], p[1]),   w01 = cvtpk2bf(p[2], p[3]);
    uint32_t w10 = cvtpk2bf(p[4], p[5]),   w11 = cvtpk2bf(p[6], p[7]);
    uint32_t w20 = cvtpk2bf(p[8], p[9]),   w21 = cvtpk2bf(p[10], p[11]);
    uint32_t w30 = cvtpk2bf(p[12], p[13]), w31 = cvtpk2bf(p[14], p[15]);
    // redistribute to A-frag layout: lane lo needs keys 8lo..8lo+7 (pa0), +32 (pa1)
    asm volatile("v_permlane32_swap_b32 %0, %1" : "+v"(w00), "+v"(w10));
    asm volatile("v_permlane16_swap_b32 %0, %1" : "+v"(w00), "+v"(w10));  // w00=d0 w10=d2
    asm volatile("v_permlane32_swap_b32 %0, %1" : "+v"(w01), "+v"(w11));
    asm volatile("v_permlane16_swap_b32 %0, %1" : "+v"(w01), "+v"(w11));  // w01=d1 w11=d3
    asm volatile("v_permlane32_swap_b32 %0, %1" : "+v"(w20), "+v"(w30));
    asm volatile("v_permlane16_swap_b32 %0, %1" : "+v"(w20), "+v"(w30));
    asm volatile("v_permlane32_swap_b32 %0, %1" : "+v"(w21), "+v"(w31));
    asm volatile("v_permlane16_swap_b32 %0, %1" : "+v"(w21), "+v"(w31));
    u32x4 pq0; pq0[0] = w00; pq0[1] = w01; pq0[2] = w10; pq0[3] = w11;
    u32x4 pq1; pq1[0] = w20; pq1[1] = w21; pq1[2] = w30; pq1[3] = w31;
    const bf16x8 pa0 = __builtin_bit_cast(bf16x8, pq0);
    const bf16x8 pa1 = __builtin_bit_cast(bf16x8, pq1);
    const u16* VsC = Vs[cur];
    __builtin_amdgcn_s_setprio(1);
#pragma unroll
    for (int nj = 0; nj < 4; ++nj) {
      const int vr = nj * 16 + lr;   // d row
      const bf16x8 bv0 = *reinterpret_cast<const bf16x8*>((const char*)VsC + vr * 128 + ((lo ^ (vr & 7)) * 16));
      const bf16x8 bv1 = *reinterpret_cast<const bf16x8*>((const char*)VsC + vr * 128 + (((4 + lo) ^ (vr & 7)) * 16));
      acc[nj] = __builtin_amdgcn_mfma_f32_16x16x32_bf16(pa0, bv0, acc[nj], 0, 0, 0);
      acc[nj] = __builtin_amdgcn_mfma_f32_16x16x32_bf16(pa1, bv1, acc[nj], 0, 0, 0);
    }
    __builtin_amdgcn_s_setprio(0);
    cur ^= 1;
  }
  float lf[4];
#pragma unroll
  for (int r = 0; r < 4; ++r) lf[r] = 1.0f / __shfl(lsum, lo * 4 + r, 64);
  const size_t orow = (size_t)b * S + qt * 128 + w * 16 + lo * 4;
#pragma unroll
  for (int nj = 0; nj < 4; ++nj) {
    const int col = h * 64 + nj * 16 + lr;
#pragma unroll
    for (int r = 0; r < 4; ++r)
      Oa[(orow + r) * 2048 + col] = f2bf(acc[nj][r] * lf[r]);
  }
}

// ---------------- host ----------------
extern "C" void kernel_launch(void* const* d_in, const int* in_sizes, int n_in,
                              void* d_out, int out_size, void* d_ws, size_t ws_size,
                              hipStream_t stream) {
  const float* x  = (const float*)d_in[0];
  const float* Wq = (const float*)d_in[1];
  const float* bq = (const float*)d_in[2];
  const float* Wk = (const float*)d_in[3];
  const float* bk = (const float*)d_in[4];
  const float* Wv = (const float*)d_in[5];
  const float* bv = (const float*)d_in[6];
  const float* Wo = (const float*)d_in[7];
  const float* bo = (const float*)d_in[8];
  float* out = (float*)d_out;
  char* ws = (char*)d_ws;

  u16*   xb    = (u16*)(ws + 0);           // [4096][2048] bf16   16.78 MB (dead after QKV GEMM)
  u16*   vtg   = (u16*)(ws + 0);           // [2][8][64][2048] bf16 4 MB — aliases xb (written after GEMM)
  u16*   wqkvT = (u16*)(ws + 16777216);    // [3072][2048] bf16   12.58 MB
  u16*   woT   = (u16*)(ws + 29360128);    // [2048][2048] bf16    8.39 MB
  u16*   qkv   = (u16*)(ws + 37748736);    // [4096][3072] bf16   25.17 MB
  u16*   attn  = (u16*)(ws + 62914560);    // [4096][2048] bf16   16.78 MB

  const float SCL = 0.125f * 1.44269504088896341f;  // 1/sqrt(64) * log2(e)

  k_cast<<<4096, 256, 0, stream>>>(x, xb, 1048576);
  k_transpose_all<<<dim3(32, 32, 4), 256, 0, stream>>>(Wq, Wk, Wv, Wo, wqkvT, woT);
  k_gemm<false><<<dim3(24, 32), 256, 0, stream>>>(xb, wqkvT, bq, bk, bv, qkv,
                                                  4096, 3072, 2048, 2048, 2560, 2048, SCL);
  k_transpose_v<<<dim3(32, 8, 2), 256, 0, stream>>>(qkv, vtg);
  k_attn<<<dim3(16, 32, 2), 512, 0, stream>>>(qkv, vtg, attn);
  k_gemm<true><<<dim3(16, 32), 256, 0, stream>>>(attn, woT, bo, bo, bo, out,
                                                 4096, 2048, 2048, 2048, 4096, 0, 1.0f);
}

// Round 14
// 271.478 us; speedup vs baseline: 1.1210x; 1.0537x over previous
//
#include <hip/hip_runtime.h>
#include <cstdint>
#include <cstddef>

typedef unsigned short u16;
typedef __bf16 bf16x8 __attribute__((ext_vector_type(8)));
typedef float f32x4 __attribute__((ext_vector_type(4)));
typedef unsigned short u16x4 __attribute__((ext_vector_type(4)));
typedef unsigned short u16x8 __attribute__((ext_vector_type(8)));
typedef uint32_t u32x4 __attribute__((ext_vector_type(4)));
typedef __attribute__((address_space(1))) unsigned int as1_uint;
typedef __attribute__((address_space(3))) unsigned int as3_uint;

__device__ __forceinline__ u16 f2bf(float f) {
  uint32_t u = __builtin_bit_cast(uint32_t, f);
  u += 0x7FFFu + ((u >> 16) & 1u);   // RNE to bf16
  return (u16)(u >> 16);
}

// one-instruction packed f32x2 -> bf16x2 (RNE), T12 recipe
__device__ __forceinline__ uint32_t cvtpk2bf(float a, float b) {
  uint32_t r;
  asm("v_cvt_pk_bf16_f32 %0, %1, %2" : "=v"(r) : "v"(a), "v"(b));
  return r;
}

__device__ __forceinline__ float max3f(float a, float b, float c) {
  return fmaxf(fmaxf(a, b), c);   // clang fuses to v_max3_f32
}

__device__ __forceinline__ void gld_lds16(const void* g, void* l) {
  __builtin_amdgcn_global_load_lds((as1_uint*)g, (as3_uint*)l, 16, 0, 0);
}

// ---------------- fused prep: weight transposes (z<4) + x cast (z>=4) ----------------
// grid (32,32,8), 256 threads.
// z=0: Wq->wqkvT[0..2048); z=1: Wo->woT; z=2: Wk->wqkvT[2048..); z=3: Wv->wqkvT[2560..);
// z in [4,8): cast slice of x (f32 -> bf16), 2048 elems/block.
__global__ __launch_bounds__(256) void k_prep(const float* __restrict__ x,
                                              u16* __restrict__ xb,
                                              const float* __restrict__ Wq,
                                              const float* __restrict__ Wk,
                                              const float* __restrict__ Wv,
                                              const float* __restrict__ Wo,
                                              u16* __restrict__ wqkvT,
                                              u16* __restrict__ woT) {
  constexpr int K = 2048;
  const int z = blockIdx.z;
  if (z >= 4) {
    int i = ((z - 4) * 1024 + blockIdx.y * 32 + blockIdx.x) * 256 + threadIdx.x;
    const float4* p = reinterpret_cast<const float4*>(x) + (size_t)i * 2;
    float4 a = p[0], b = p[1];
    u16x8 r;
    r[0] = f2bf(a.x); r[1] = f2bf(a.y); r[2] = f2bf(a.z); r[3] = f2bf(a.w);
    r[4] = f2bf(b.x); r[5] = f2bf(b.y); r[6] = f2bf(b.z); r[7] = f2bf(b.w);
    *reinterpret_cast<u16x8*>(xb + (size_t)i * 8) = r;
    return;
  }
  const float* W; u16* Wt; int N;
  if (z == 0)      { W = Wq; Wt = wqkvT;                        N = 2048; }
  else if (z == 1) { W = Wo; Wt = woT;                          N = 2048; }
  else if (z == 2) { W = Wk; Wt = wqkvT + (size_t)2048 * 2048;  N = 512;  }
  else             { W = Wv; Wt = wqkvT + (size_t)2560 * 2048;  N = 512;  }
  const int n0 = blockIdx.x * 64;
  if (n0 >= N) return;
  __shared__ u16 tile[64][72];
  const int k0 = blockIdx.y * 64;
  const int r = threadIdx.x >> 4;
  const int c4 = (threadIdx.x & 15) * 4;
#pragma unroll
  for (int i = 0; i < 4; ++i) {
    int kk = r + i * 16;
    float4 v = *reinterpret_cast<const float4*>(W + (size_t)(k0 + kk) * N + n0 + c4);
    tile[kk][c4 + 0] = f2bf(v.x); tile[kk][c4 + 1] = f2bf(v.y);
    tile[kk][c4 + 2] = f2bf(v.z); tile[kk][c4 + 3] = f2bf(v.w);
  }
  __syncthreads();
#pragma unroll
  for (int i = 0; i < 4; ++i) {
    int nn = r + i * 16;
    u16x4 o;
    o[0] = tile[c4 + 0][nn]; o[1] = tile[c4 + 1][nn];
    o[2] = tile[c4 + 2][nn]; o[3] = tile[c4 + 3][nn];
    *reinterpret_cast<u16x4*>(Wt + (size_t)(n0 + nn) * K + k0 + c4) = o;
  }
}

// ---------------- V-part of qkv -> Vt_g[b][kvh][d][token] ----------------
__global__ __launch_bounds__(256) void k_transpose_v(const u16* __restrict__ qkv,
                                                     u16* __restrict__ vt) {
  __shared__ u16 tile[64][72];
  const int t0 = blockIdx.x * 64, kvh = blockIdx.y, b = blockIdx.z;
  const u16* src = qkv + ((size_t)(b * 2048) + t0) * 3072 + 2560 + kvh * 64;
  u16* dst = vt + ((size_t)(b * 8 + kvh) * 64) * 2048 + t0;
  const int r = threadIdx.x >> 3;          // 0..31
  const int c8 = (threadIdx.x & 7) * 8;    // 0..56
#pragma unroll
  for (int i = 0; i < 2; ++i) {
    int rr = r + i * 32;                   // token row
    u16x8 v = *reinterpret_cast<const u16x8*>(src + (size_t)rr * 3072 + c8);
#pragma unroll
    for (int j = 0; j < 8; ++j) tile[c8 + j][rr] = v[j];
  }
  __syncthreads();
#pragma unroll
  for (int i = 0; i < 2; ++i) {
    int rr = r + i * 32;                   // d row
    u16x8 o;
#pragma unroll
    for (int j = 0; j < 8; ++j) o[j] = tile[rr][c8 + j];
    *reinterpret_cast<u16x8*>(dst + (size_t)rr * 2048 + c8) = o;
  }
}

// ---------------- bf16 GEMM: C = (A @ Bt^T + bias(col)) * colscale ----------------
// 128x128 tile, BK=64, 4 waves (2x2), 16x16x32 MFMA; T1 bijective XCD swizzle (nwg%8==0).
template <bool F32OUT>
__global__ __launch_bounds__(256) void k_gemm(const u16* __restrict__ A,
                                              const u16* __restrict__ Bt,
                                              const float* __restrict__ b0,
                                              const float* __restrict__ b1,
                                              const float* __restrict__ b2,
                                              void* __restrict__ Cout,
                                              int M, int N, int K,
                                              int n1, int n2,
                                              int scaleN, float scaleV) {
  __shared__ __align__(16) u16 As[128 * 64];
  __shared__ __align__(16) u16 Bs[128 * 64];
  const int id = blockIdx.y * gridDim.x + blockIdx.x;
  const int cpx = (gridDim.x * gridDim.y) >> 3;
  const int nid = (id & 7) * cpx + (id >> 3);
  const int m0 = (nid / gridDim.x) * 128, n0 = (nid % gridDim.x) * 128;
  const int tid = threadIdx.x;
  const int l = tid & 63, w = tid >> 6;
  const int wm = w >> 1, wn = w & 1;
  const int lr = l & 15, lo = l >> 4;
  const int srow = w * 8 + (l >> 3);
  const int sc = (l & 7) ^ ((l >> 3) & 7);
  f32x4 acc[4][4] = {};
  for (int kt = 0; kt < K; kt += 64) {
    __syncthreads();
#pragma unroll
    for (int it = 0; it < 4; ++it) {
      int row = it * 32 + srow;
      gld_lds16(A + (size_t)(m0 + row) * K + kt + sc * 8,
                (char*)As + (it * 32 + w * 8) * 128);
      gld_lds16(Bt + (size_t)(n0 + row) * K + kt + sc * 8,
                (char*)Bs + (it * 32 + w * 8) * 128);
    }
    __syncthreads();
    bf16x8 af[4][2], bfr[4][2];
#pragma unroll
    for (int mi = 0; mi < 4; ++mi) {
      int row = wm * 64 + mi * 16 + lr;
#pragma unroll
      for (int ks = 0; ks < 2; ++ks) {
        int ch = (ks * 4 + lo) ^ (row & 7);
        af[mi][ks] = *reinterpret_cast<const bf16x8*>((const char*)As + row * 128 + ch * 16);
      }
    }
#pragma unroll
    for (int nj = 0; nj < 4; ++nj) {
      int row = wn * 64 + nj * 16 + lr;
#pragma unroll
      for (int ks = 0; ks < 2; ++ks) {
        int ch = (ks * 4 + lo) ^ (row & 7);
        bfr[nj][ks] = *reinterpret_cast<const bf16x8*>((const char*)Bs + row * 128 + ch * 16);
      }
    }
#pragma unroll
    for (int mi = 0; mi < 4; ++mi)
#pragma unroll
      for (int nj = 0; nj < 4; ++nj) {
        acc[mi][nj] = __builtin_amdgcn_mfma_f32_16x16x32_bf16(af[mi][0], bfr[nj][0], acc[mi][nj], 0, 0, 0);
        acc[mi][nj] = __builtin_amdgcn_mfma_f32_16x16x32_bf16(af[mi][1], bfr[nj][1], acc[mi][nj], 0, 0, 0);
      }
  }
#pragma unroll
  for (int mi = 0; mi < 4; ++mi) {
    int row = m0 + wm * 64 + mi * 16 + lo * 4;
#pragma unroll
    for (int nj = 0; nj < 4; ++nj) {
      int col = n0 + wn * 64 + nj * 16 + lr;
      float bv = (col < n1) ? b0[col] : (col < n2 ? b1[col - n1] : b2[col - n2]);
      float scc = (col < scaleN) ? scaleV : 1.0f;
#pragma unroll
      for (int r = 0; r < 4; ++r) {
        float v = (acc[mi][nj][r] + bv) * scc;
        if (F32OUT) ((float*)Cout)[(size_t)(row + r) * N + col] = v;
        else        ((u16*)Cout)[(size_t)(row + r) * N + col] = f2bf(v);
      }
    }
  }
}

// ---------------- flash attention: 512 threads, 8 waves x 16 q-rows ----------------
// grid (S/128, NQ, B); KVBLK=64; HD=64. launch_bounds(512,2).
// lsum via MFMA: lsum4 = mfma(pa, ones, lsum4) gives row-sums in ACC layout
// (lane(lo,lr) -> q=lo*4+r), replacing the 15-add+2-shfl VALU tree per tile.
__global__ __launch_bounds__(512, 2) void k_attn(const u16* __restrict__ QKV,
                                                 const u16* __restrict__ VT,
                                                 u16* __restrict__ Oa) {
  constexpr int S = 2048, LDQ = 3072;
  constexpr float THR = 8.0f;
  __shared__ __align__(16) u16 Ks[2][64 * 64];   // [key][d], chunk ^= row&7
  __shared__ __align__(16) u16 Vs[2][64 * 64];   // [d][key], chunk ^= row&7
  const int qt = blockIdx.x, h = blockIdx.y, b = blockIdx.z;
  const int kvh = h >> 2;
  const int tid = threadIdx.x, l = tid & 63, w = tid >> 6;   // w = 0..7
  const int lr = l & 15, lo = l >> 4;
  const size_t base = (size_t)b * S * LDQ;
  const u16* Qg = QKV + base + h * 64;
  const u16* Kg = QKV + base + 2048 + kvh * 64;
  const u16* Vg = VT + (size_t)(b * 8 + kvh) * 64 * 2048;
  const int qrow = qt * 128 + w * 16 + lr;
  const bf16x8 aq0 = *reinterpret_cast<const bf16x8*>(Qg + (size_t)qrow * LDQ + lo * 8);
  const bf16x8 aq1 = *reinterpret_cast<const bf16x8*>(Qg + (size_t)qrow * LDQ + 32 + lo * 8);
  // all-ones bf16 B-frag (layout-proof: every element 1.0)
  u32x4 onesw; onesw[0] = 0x3F803F80u; onesw[1] = 0x3F803F80u; onesw[2] = 0x3F803F80u; onesw[3] = 0x3F803F80u;
  const bf16x8 ones = __builtin_bit_cast(bf16x8, onesw);
  f32x4 acc[4] = {};
  f32x4 lsum4 = {};                              // row-sum in acc layout: lsum4[r] for q=lo*4+r
  float mrun = -1e30f;
  const int krow = tid >> 3;                     // rows 0..63 across 8 waves
  const int ksc = (l & 7) ^ ((l >> 3) & 7);
  // ---- prologue: stage tile 0 (1 issue per operand covers all 64 rows) ----
  gld_lds16(Kg + (size_t)krow * LDQ + ksc * 8, (char*)Ks[0] + (w * 8) * 128);
  gld_lds16(Vg + (size_t)krow * 2048 + ksc * 8, (char*)Vs[0] + (w * 8) * 128);
  int cur = 0;
  for (int kt = 0; kt < S; kt += 64) {
    __syncthreads();   // implicit vmcnt(0): buf[cur] (K+V) ready
    if (kt + 64 < S) { // prefetch tile t+1; in flight across compute(t)
      const int nb = cur ^ 1, nk = kt + 64;
      gld_lds16(Kg + (size_t)(nk + krow) * LDQ + ksc * 8, (char*)Ks[nb] + (w * 8) * 128);
      gld_lds16(Vg + (size_t)krow * 2048 + nk + ksc * 8, (char*)Vs[nb] + (w * 8) * 128);
    }
    // QK^T swapped: p[t*4+r] = S[key=16t+4lo+r][q=lr]  (Q pre-scaled by log2e/sqrt(HD))
    float p[16];
    const u16* KsC = Ks[cur];
    __builtin_amdgcn_s_setprio(1);
#pragma unroll
    for (int t = 0; t < 4; ++t) {
      const int row = t * 16 + lr;
      bf16x8 k0 = *reinterpret_cast<const bf16x8*>((const char*)KsC + row * 128 + ((lo ^ (row & 7)) * 16));
      bf16x8 k1 = *reinterpret_cast<const bf16x8*>((const char*)KsC + row * 128 + (((4 + lo) ^ (row & 7)) * 16));
      f32x4 zz = {};
      zz = __builtin_amdgcn_mfma_f32_16x16x32_bf16(k0, aq0, zz, 0, 0, 0);
      zz = __builtin_amdgcn_mfma_f32_16x16x32_bf16(k1, aq1, zz, 0, 0, 0);
#pragma unroll
      for (int r = 0; r < 4; ++r) p[t * 4 + r] = zz[r];
    }
    __builtin_amdgcn_s_setprio(0);
    // tile max for q=lr: max3 tree + 2 shfl
    float m0 = max3f(p[0], p[1], p[2]);
    float m1 = max3f(p[3], p[4], p[5]);
    float m2 = max3f(p[6], p[7], p[8]);
    float m3 = max3f(p[9], p[10], p[11]);
    float m4 = max3f(p[12], p[13], p[14]);
    float tm = fmaxf(max3f(m0, m1, m2), max3f(m3, m4, p[15]));
    tm = fmaxf(tm, __shfl_xor(tm, 16, 64));
    tm = fmaxf(tm, __shfl_xor(tm, 32, 64));
    if (__all(tm <= mrun + THR)) {
      // defer-max: keep stale mrun; p bounded by 2^THR
#pragma unroll
      for (int i = 0; i < 16; ++i) p[i] = __builtin_amdgcn_exp2f(p[i] - mrun);
    } else {
      float mnew = fmaxf(mrun, tm);
      float alpha = __builtin_amdgcn_exp2f(mrun - mnew);
      mrun = mnew;
#pragma unroll
      for (int i = 0; i < 16; ++i) p[i] = __builtin_amdgcn_exp2f(p[i] - mnew);
#pragma unroll
      for (int r = 0; r < 4; ++r) {
        float ar = __shfl(alpha, lo * 4 + r, 64);   // alpha for acc-row q=lo*4+r
        lsum4[r] *= ar;
#pragma unroll
        for (int nj = 0; nj < 4; ++nj) acc[nj][r] *= ar;
      }
    }
    // pack P pairs with v_cvt_pk_bf16_f32 (1 instr each)
    uint32_t w00 = cvtpk2bf(p[0], p[1]),   w01 = cvtpk2bf(p[2], p[3]);
    uint32_t w10 = cvtpk2bf(p[4], p[5]),   w11 = cvtpk2bf(p[6], p[7]);
    uint32_t w20 = cvtpk2bf(p[8], p[9]),   w21 = cvtpk2bf(p[10], p[11]);
    uint32_t w30 = cvtpk2bf(p[12], p[13]), w31 = cvtpk2bf(p[14], p[15]);
    // redistribute to A-frag layout: lane lo needs keys 8lo..8lo+7 (pa0), +32 (pa1)
    asm volatile("v_permlane32_swap_b32 %0, %1" : "+v"(w00), "+v"(w10));
    asm volatile("v_permlane16_swap_b32 %0, %1" : "+v"(w00), "+v"(w10));  // w00=d0 w10=d2
    asm volatile("v_permlane32_swap_b32 %0, %1" : "+v"(w01), "+v"(w11));
    asm volatile("v_permlane16_swap_b32 %0, %1" : "+v"(w01), "+v"(w11));  // w01=d1 w11=d3
    asm volatile("v_permlane32_swap_b32 %0, %1" : "+v"(w20), "+v"(w30));
    asm volatile("v_permlane16_swap_b32 %0, %1" : "+v"(w20), "+v"(w30));
    asm volatile("v_permlane32_swap_b32 %0, %1" : "+v"(w21), "+v"(w31));
    asm volatile("v_permlane16_swap_b32 %0, %1" : "+v"(w21), "+v"(w31));
    u32x4 pq0; pq0[0] = w00; pq0[1] = w01; pq0[2] = w10; pq0[3] = w11;
    u32x4 pq1; pq1[0] = w20; pq1[1] = w21; pq1[2] = w30; pq1[3] = w31;
    const bf16x8 pa0 = __builtin_bit_cast(bf16x8, pq0);
    const bf16x8 pa1 = __builtin_bit_cast(bf16x8, pq1);
    const u16* VsC = Vs[cur];
    __builtin_amdgcn_s_setprio(1);
    // row-sum via MFMA (replaces VALU add-tree): lsum4[r] += sum_k P[q=lo*4+r][k]
    lsum4 = __builtin_amdgcn_mfma_f32_16x16x32_bf16(pa0, ones, lsum4, 0, 0, 0);
    lsum4 = __builtin_amdgcn_mfma_f32_16x16x32_bf16(pa1, ones, lsum4, 0, 0, 0);
#pragma unroll
    for (int nj = 0; nj < 4; ++nj) {
      const int vr = nj * 16 + lr;   // d row
      const bf16x8 bv0 = *reinterpret_cast<const bf16x8*>((const char*)VsC + vr * 128 + ((lo ^ (vr & 7)) * 16));
      const bf16x8 bv1 = *reinterpret_cast<const bf16x8*>((const char*)VsC + vr * 128 + (((4 + lo) ^ (vr & 7)) * 16));
      acc[nj] = __builtin_amdgcn_mfma_f32_16x16x32_bf16(pa0, bv0, acc[nj], 0, 0, 0);
      acc[nj] = __builtin_amdgcn_mfma_f32_16x16x32_bf16(pa1, bv1, acc[nj], 0, 0, 0);
    }
    __builtin_amdgcn_s_setprio(0);
    cur ^= 1;
  }
  float lf[4];
#pragma unroll
  for (int r = 0; r < 4; ++r) lf[r] = 1.0f / lsum4[r];
  const size_t orow = (size_t)b * S + qt * 128 + w * 16 + lo * 4;
#pragma unroll
  for (int nj = 0; nj < 4; ++nj) {
    const int col = h * 64 + nj * 16 + lr;
#pragma unroll
    for (int r = 0; r < 4; ++r)
      Oa[(orow + r) * 2048 + col] = f2bf(acc[nj][r] * lf[r]);
  }
}

// ---------------- host ----------------
extern "C" void kernel_launch(void* const* d_in, const int* in_sizes, int n_in,
                              void* d_out, int out_size, void* d_ws, size_t ws_size,
                              hipStream_t stream) {
  const float* x  = (const float*)d_in[0];
  const float* Wq = (const float*)d_in[1];
  const float* bq = (const float*)d_in[2];
  const float* Wk = (const float*)d_in[3];
  const float* bk = (const float*)d_in[4];
  const float* Wv = (const float*)d_in[5];
  const float* bv = (const float*)d_in[6];
  const float* Wo = (const float*)d_in[7];
  const float* bo = (const float*)d_in[8];
  float* out = (float*)d_out;
  char* ws = (char*)d_ws;

  u16*   xb    = (u16*)(ws + 0);           // [4096][2048] bf16   16.78 MB (dead after QKV GEMM)
  u16*   vtg   = (u16*)(ws + 0);           // [2][8][64][2048] bf16 4 MB — aliases xb (written after GEMM)
  u16*   wqkvT = (u16*)(ws + 16777216);    // [3072][2048] bf16   12.58 MB
  u16*   woT   = (u16*)(ws + 29360128);    // [2048][2048] bf16    8.39 MB
  u16*   qkv   = (u16*)(ws + 37748736);    // [4096][3072] bf16   25.17 MB
  u16*   attn  = (u16*)(ws + 62914560);    // [4096][2048] bf16   16.78 MB

  const float SCL = 0.125f * 1.44269504088896341f;  // 1/sqrt(64) * log2(e)

  k_prep<<<dim3(32, 32, 8), 256, 0, stream>>>(x, xb, Wq, Wk, Wv, Wo, wqkvT, woT);
  k_gemm<false><<<dim3(24, 32), 256, 0, stream>>>(xb, wqkvT, bq, bk, bv, qkv,
                                                  4096, 3072, 2048, 2048, 2560, 2048, SCL);
  k_transpose_v<<<dim3(32, 8, 2), 256, 0, stream>>>(qkv, vtg);
  k_attn<<<dim3(16, 32, 2), 512, 0, stream>>>(qkv, vtg, attn);
  k_gemm<true><<<dim3(16, 32), 256, 0, stream>>>(attn, woT, bo, bo, bo, out,
                                                 4096, 2048, 2048, 2048, 4096, 0, 1.0f);
}

// Round 15
// 253.267 us; speedup vs baseline: 1.2016x; 1.0719x over previous
//
#include <hip/hip_runtime.h>
#include <cstdint>
#include <cstddef>

typedef unsigned short u16;
typedef __bf16 bf16x8 __attribute__((ext_vector_type(8)));
typedef float f32x4 __attribute__((ext_vector_type(4)));
typedef unsigned short u16x4 __attribute__((ext_vector_type(4)));
typedef unsigned short u16x8 __attribute__((ext_vector_type(8)));
typedef uint32_t u32x4 __attribute__((ext_vector_type(4)));
typedef __attribute__((address_space(1))) unsigned int as1_uint;
typedef __attribute__((address_space(3))) unsigned int as3_uint;

__device__ __forceinline__ u16 f2bf(float f) {
  uint32_t u = __builtin_bit_cast(uint32_t, f);
  u += 0x7FFFu + ((u >> 16) & 1u);   // RNE to bf16
  return (u16)(u >> 16);
}

// one-instruction packed f32x2 -> bf16x2 (RNE), T12 recipe
__device__ __forceinline__ uint32_t cvtpk2bf(float a, float b) {
  uint32_t r;
  asm("v_cvt_pk_bf16_f32 %0, %1, %2" : "=v"(r) : "v"(a), "v"(b));
  return r;
}

__device__ __forceinline__ float max3f(float a, float b, float c) {
  return fmaxf(fmaxf(a, b), c);   // clang fuses to v_max3_f32
}

__device__ __forceinline__ void gld_lds16(const void* g, void* l) {
  __builtin_amdgcn_global_load_lds((as1_uint*)g, (as3_uint*)l, 16, 0, 0);
}

// ---------------- fused prep: weight transposes (z<4) + x cast (z>=4) ----------------
__global__ __launch_bounds__(256) void k_prep(const float* __restrict__ x,
                                              u16* __restrict__ xb,
                                              const float* __restrict__ Wq,
                                              const float* __restrict__ Wk,
                                              const float* __restrict__ Wv,
                                              const float* __restrict__ Wo,
                                              u16* __restrict__ wqkvT,
                                              u16* __restrict__ woT) {
  constexpr int K = 2048;
  const int z = blockIdx.z;
  if (z >= 4) {
    int i = ((z - 4) * 1024 + blockIdx.y * 32 + blockIdx.x) * 256 + threadIdx.x;
    const float4* p = reinterpret_cast<const float4*>(x) + (size_t)i * 2;
    float4 a = p[0], b = p[1];
    u16x8 r;
    r[0] = f2bf(a.x); r[1] = f2bf(a.y); r[2] = f2bf(a.z); r[3] = f2bf(a.w);
    r[4] = f2bf(b.x); r[5] = f2bf(b.y); r[6] = f2bf(b.z); r[7] = f2bf(b.w);
    *reinterpret_cast<u16x8*>(xb + (size_t)i * 8) = r;
    return;
  }
  const float* W; u16* Wt; int N;
  if (z == 0)      { W = Wq; Wt = wqkvT;                        N = 2048; }
  else if (z == 1) { W = Wo; Wt = woT;                          N = 2048; }
  else if (z == 2) { W = Wk; Wt = wqkvT + (size_t)2048 * 2048;  N = 512;  }
  else             { W = Wv; Wt = wqkvT + (size_t)2560 * 2048;  N = 512;  }
  const int n0 = blockIdx.x * 64;
  if (n0 >= N) return;
  __shared__ u16 tile[64][72];
  const int k0 = blockIdx.y * 64;
  const int r = threadIdx.x >> 4;
  const int c4 = (threadIdx.x & 15) * 4;
#pragma unroll
  for (int i = 0; i < 4; ++i) {
    int kk = r + i * 16;
    float4 v = *reinterpret_cast<const float4*>(W + (size_t)(k0 + kk) * N + n0 + c4);
    tile[kk][c4 + 0] = f2bf(v.x); tile[kk][c4 + 1] = f2bf(v.y);
    tile[kk][c4 + 2] = f2bf(v.z); tile[kk][c4 + 3] = f2bf(v.w);
  }
  __syncthreads();
#pragma unroll
  for (int i = 0; i < 4; ++i) {
    int nn = r + i * 16;
    u16x4 o;
    o[0] = tile[c4 + 0][nn]; o[1] = tile[c4 + 1][nn];
    o[2] = tile[c4 + 2][nn]; o[3] = tile[c4 + 3][nn];
    *reinterpret_cast<u16x4*>(Wt + (size_t)(n0 + nn) * K + k0 + c4) = o;
  }
}

// ---------------- bf16 GEMM: C = (A @ Bt^T + bias(col)) * colscale ----------------
// 128x128 tile, BK=64, 4 waves (2x2), 16x16x32 MFMA; T1 bijective XCD swizzle.
// ldC: row stride of C. Columns >= vcol0 (bf16 out only) are written TRANSPOSED to
// vout[b][kvh][d][token] (fuses the old k_transpose_v into the epilogue).
template <bool F32OUT>
__global__ __launch_bounds__(256) void k_gemm(const u16* __restrict__ A,
                                              const u16* __restrict__ Bt,
                                              const float* __restrict__ b0,
                                              const float* __restrict__ b1,
                                              const float* __restrict__ b2,
                                              void* __restrict__ Cout,
                                              int M, int N, int K,
                                              int n1, int n2,
                                              int scaleN, float scaleV,
                                              u16* __restrict__ vout, int vcol0, int ldC) {
  __shared__ __align__(16) u16 As[128 * 64];
  __shared__ __align__(16) u16 Bs[128 * 64];
  const int id = blockIdx.y * gridDim.x + blockIdx.x;
  const int cpx = (gridDim.x * gridDim.y) >> 3;
  const int nid = (id & 7) * cpx + (id >> 3);
  const int m0 = (nid / gridDim.x) * 128, n0 = (nid % gridDim.x) * 128;
  const int tid = threadIdx.x;
  const int l = tid & 63, w = tid >> 6;
  const int wm = w >> 1, wn = w & 1;
  const int lr = l & 15, lo = l >> 4;
  const int srow = w * 8 + (l >> 3);
  const int sc = (l & 7) ^ ((l >> 3) & 7);
  f32x4 acc[4][4] = {};
  for (int kt = 0; kt < K; kt += 64) {
    __syncthreads();
#pragma unroll
    for (int it = 0; it < 4; ++it) {
      int row = it * 32 + srow;
      gld_lds16(A + (size_t)(m0 + row) * K + kt + sc * 8,
                (char*)As + (it * 32 + w * 8) * 128);
      gld_lds16(Bt + (size_t)(n0 + row) * K + kt + sc * 8,
                (char*)Bs + (it * 32 + w * 8) * 128);
    }
    __syncthreads();
    bf16x8 af[4][2], bfr[4][2];
#pragma unroll
    for (int mi = 0; mi < 4; ++mi) {
      int row = wm * 64 + mi * 16 + lr;
#pragma unroll
      for (int ks = 0; ks < 2; ++ks) {
        int ch = (ks * 4 + lo) ^ (row & 7);
        af[mi][ks] = *reinterpret_cast<const bf16x8*>((const char*)As + row * 128 + ch * 16);
      }
    }
#pragma unroll
    for (int nj = 0; nj < 4; ++nj) {
      int row = wn * 64 + nj * 16 + lr;
#pragma unroll
      for (int ks = 0; ks < 2; ++ks) {
        int ch = (ks * 4 + lo) ^ (row & 7);
        bfr[nj][ks] = *reinterpret_cast<const bf16x8*>((const char*)Bs + row * 128 + ch * 16);
      }
    }
#pragma unroll
    for (int mi = 0; mi < 4; ++mi)
#pragma unroll
      for (int nj = 0; nj < 4; ++nj) {
        acc[mi][nj] = __builtin_amdgcn_mfma_f32_16x16x32_bf16(af[mi][0], bfr[nj][0], acc[mi][nj], 0, 0, 0);
        acc[mi][nj] = __builtin_amdgcn_mfma_f32_16x16x32_bf16(af[mi][1], bfr[nj][1], acc[mi][nj], 0, 0, 0);
      }
  }
#pragma unroll
  for (int mi = 0; mi < 4; ++mi) {
    int row = m0 + wm * 64 + mi * 16 + lo * 4;
#pragma unroll
    for (int nj = 0; nj < 4; ++nj) {
      int col = n0 + wn * 64 + nj * 16 + lr;
      float bv = (col < n1) ? b0[col] : (col < n2 ? b1[col - n1] : b2[col - n2]);
      float scc = (col < scaleN) ? scaleV : 1.0f;
      float v[4];
#pragma unroll
      for (int r = 0; r < 4; ++r) v[r] = (acc[mi][nj][r] + bv) * scc;
      if (!F32OUT && col >= vcol0) {
        // V-part: write transposed to vout[b][kvh][d][token] (4 consecutive tokens)
        int d = col - vcol0;
        int kvh = d >> 6, dcol = d & 63;
        int bb = row >> 11, token = row & 2047;
        u16x4 o;
#pragma unroll
        for (int r = 0; r < 4; ++r) o[r] = f2bf(v[r]);
        *reinterpret_cast<u16x4*>(vout + (((size_t)(bb * 8 + kvh) * 64 + dcol) * 2048 + token)) = o;
      } else {
#pragma unroll
        for (int r = 0; r < 4; ++r) {
          if (F32OUT) ((float*)Cout)[(size_t)(row + r) * ldC + col] = v[r];
          else        ((u16*)Cout)[(size_t)(row + r) * ldC + col] = f2bf(v[r]);
        }
      }
    }
  }
}

// ---------------- flash attention: 512 threads, 8 waves x 16 q-rows ----------------
// grid (S/128, NQ, B) = 1024 blocks; KVBLK=64; HD=64. launch_bounds(512,4):
// natural VGPR 48-52 <= cap 64 (cap = 256/waves_per_EU) -> no spill, and
// 4 blocks/CU x 8 waves = 32 waves/CU (2x R14's occupancy; LDS 32KB*4=128<=160KB).
// lsum via MFMA (acc-layout row sums); qkv is [4096][2560] (V lives in vtg).
__global__ __launch_bounds__(512, 4) void k_attn(const u16* __restrict__ QKV,
                                                 const u16* __restrict__ VT,
                                                 u16* __restrict__ Oa) {
  constexpr int S = 2048, LDQ = 2560;
  constexpr float THR = 8.0f;
  __shared__ __align__(16) u16 Ks[2][64 * 64];   // [key][d], chunk ^= row&7
  __shared__ __align__(16) u16 Vs[2][64 * 64];   // [d][key], chunk ^= row&7
  const int qt = blockIdx.x, h = blockIdx.y, b = blockIdx.z;
  const int kvh = h >> 2;
  const int tid = threadIdx.x, l = tid & 63, w = tid >> 6;   // w = 0..7
  const int lr = l & 15, lo = l >> 4;
  const size_t base = (size_t)b * S * LDQ;
  const u16* Qg = QKV + base + h * 64;
  const u16* Kg = QKV + base + 2048 + kvh * 64;
  const u16* Vg = VT + (size_t)(b * 8 + kvh) * 64 * 2048;
  const int qrow = qt * 128 + w * 16 + lr;
  const bf16x8 aq0 = *reinterpret_cast<const bf16x8*>(Qg + (size_t)qrow * LDQ + lo * 8);
  const bf16x8 aq1 = *reinterpret_cast<const bf16x8*>(Qg + (size_t)qrow * LDQ + 32 + lo * 8);
  // all-ones bf16 B-frag (layout-proof: every element 1.0)
  u32x4 onesw; onesw[0] = 0x3F803F80u; onesw[1] = 0x3F803F80u; onesw[2] = 0x3F803F80u; onesw[3] = 0x3F803F80u;
  const bf16x8 ones = __builtin_bit_cast(bf16x8, onesw);
  f32x4 acc[4] = {};
  f32x4 lsum4 = {};                              // row-sum in acc layout: lsum4[r] for q=lo*4+r
  float mrun = -1e30f;
  const int krow = tid >> 3;                     // rows 0..63 across 8 waves
  const int ksc = (l & 7) ^ ((l >> 3) & 7);
  // ---- prologue: stage tile 0 (1 issue per operand covers all 64 rows) ----
  gld_lds16(Kg + (size_t)krow * LDQ + ksc * 8, (char*)Ks[0] + (w * 8) * 128);
  gld_lds16(Vg + (size_t)krow * 2048 + ksc * 8, (char*)Vs[0] + (w * 8) * 128);
  int cur = 0;
  for (int kt = 0; kt < S; kt += 64) {
    __syncthreads();   // implicit vmcnt(0): buf[cur] (K+V) ready
    if (kt + 64 < S) { // prefetch tile t+1; in flight across compute(t)
      const int nb = cur ^ 1, nk = kt + 64;
      gld_lds16(Kg + (size_t)(nk + krow) * LDQ + ksc * 8, (char*)Ks[nb] + (w * 8) * 128);
      gld_lds16(Vg + (size_t)krow * 2048 + nk + ksc * 8, (char*)Vs[nb] + (w * 8) * 128);
    }
    // QK^T swapped: p[t*4+r] = S[key=16t+4lo+r][q=lr]  (Q pre-scaled by log2e/sqrt(HD))
    float p[16];
    const u16* KsC = Ks[cur];
    __builtin_amdgcn_s_setprio(1);
#pragma unroll
    for (int t = 0; t < 4; ++t) {
      const int row = t * 16 + lr;
      bf16x8 k0 = *reinterpret_cast<const bf16x8*>((const char*)KsC + row * 128 + ((lo ^ (row & 7)) * 16));
      bf16x8 k1 = *reinterpret_cast<const bf16x8*>((const char*)KsC + row * 128 + (((4 + lo) ^ (row & 7)) * 16));
      f32x4 zz = {};
      zz = __builtin_amdgcn_mfma_f32_16x16x32_bf16(k0, aq0, zz, 0, 0, 0);
      zz = __builtin_amdgcn_mfma_f32_16x16x32_bf16(k1, aq1, zz, 0, 0, 0);
#pragma unroll
      for (int r = 0; r < 4; ++r) p[t * 4 + r] = zz[r];
    }
    __builtin_amdgcn_s_setprio(0);
    // tile max for q=lr: max3 tree + 2 shfl
    float m0 = max3f(p[0], p[1], p[2]);
    float m1 = max3f(p[3], p[4], p[5]);
    float m2 = max3f(p[6], p[7], p[8]);
    float m3 = max3f(p[9], p[10], p[11]);
    float m4 = max3f(p[12], p[13], p[14]);
    float tm = fmaxf(max3f(m0, m1, m2), max3f(m3, m4, p[15]));
    tm = fmaxf(tm, __shfl_xor(tm, 16, 64));
    tm = fmaxf(tm, __shfl_xor(tm, 32, 64));
    if (__all(tm <= mrun + THR)) {
      // defer-max: keep stale mrun; p bounded by 2^THR
#pragma unroll
      for (int i = 0; i < 16; ++i) p[i] = __builtin_amdgcn_exp2f(p[i] - mrun);
    } else {
      float mnew = fmaxf(mrun, tm);
      float alpha = __builtin_amdgcn_exp2f(mrun - mnew);
      mrun = mnew;
#pragma unroll
      for (int i = 0; i < 16; ++i) p[i] = __builtin_amdgcn_exp2f(p[i] - mnew);
#pragma unroll
      for (int r = 0; r < 4; ++r) {
        float ar = __shfl(alpha, lo * 4 + r, 64);   // alpha for acc-row q=lo*4+r
        lsum4[r] *= ar;
#pragma unroll
        for (int nj = 0; nj < 4; ++nj) acc[nj][r] *= ar;
      }
    }
    // pack P pairs with v_cvt_pk_bf16_f32 (1 instr each)
    uint32_t w00 = cvtpk2bf(p[0], p[1]),   w01 = cvtpk2bf(p[2], p[3]);
    uint32_t w10 = cvtpk2bf(p[4], p[5]),   w11 = cvtpk2bf(p[6], p[7]);
    uint32_t w20 = cvtpk2bf(p[8], p[9]),   w21 = cvtpk2bf(p[10], p[11]);
    uint32_t w30 = cvtpk2bf(p[12], p[13]), w31 = cvtpk2bf(p[14], p[15]);
    // redistribute to A-frag layout: lane lo needs keys 8lo..8lo+7 (pa0), +32 (pa1)
    asm volatile("v_permlane32_swap_b32 %0, %1" : "+v"(w00), "+v"(w10));
    asm volatile("v_permlane16_swap_b32 %0, %1" : "+v"(w00), "+v"(w10));  // w00=d0 w10=d2
    asm volatile("v_permlane32_swap_b32 %0, %1" : "+v"(w01), "+v"(w11));
    asm volatile("v_permlane16_swap_b32 %0, %1" : "+v"(w01), "+v"(w11));  // w01=d1 w11=d3
    asm volatile("v_permlane32_swap_b32 %0, %1" : "+v"(w20), "+v"(w30));
    asm volatile("v_permlane16_swap_b32 %0, %1" : "+v"(w20), "+v"(w30));
    asm volatile("v_permlane32_swap_b32 %0, %1" : "+v"(w21), "+v"(w31));
    asm volatile("v_permlane16_swap_b32 %0, %1" : "+v"(w21), "+v"(w31));
    u32x4 pq0; pq0[0] = w00; pq0[1] = w01; pq0[2] = w10; pq0[3] = w11;
    u32x4 pq1; pq1[0] = w20; pq1[1] = w21; pq1[2] = w30; pq1[3] = w31;
    const bf16x8 pa0 = __builtin_bit_cast(bf16x8, pq0);
    const bf16x8 pa1 = __builtin_bit_cast(bf16x8, pq1);
    const u16* VsC = Vs[cur];
    __builtin_amdgcn_s_setprio(1);
    // row-sum via MFMA (replaces VALU add-tree): lsum4[r] += sum_k P[q=lo*4+r][k]
    lsum4 = __builtin_amdgcn_mfma_f32_16x16x32_bf16(pa0, ones, lsum4, 0, 0, 0);
    lsum4 = __builtin_amdgcn_mfma_f32_16x16x32_bf16(pa1, ones, lsum4, 0, 0, 0);
#pragma unroll
    for (int nj = 0; nj < 4; ++nj) {
      const int vr = nj * 16 + lr;   // d row
      const bf16x8 bv0 = *reinterpret_cast<const bf16x8*>((const char*)VsC + vr * 128 + ((lo ^ (vr & 7)) * 16));
      const bf16x8 bv1 = *reinterpret_cast<const bf16x8*>((const char*)VsC + vr * 128 + (((4 + lo) ^ (vr & 7)) * 16));
      acc[nj] = __builtin_amdgcn_mfma_f32_16x16x32_bf16(pa0, bv0, acc[nj], 0, 0, 0);
      acc[nj] = __builtin_amdgcn_mfma_f32_16x16x32_bf16(pa1, bv1, acc[nj], 0, 0, 0);
    }
    __builtin_amdgcn_s_setprio(0);
    cur ^= 1;
  }
  float lf[4];
#pragma unroll
  for (int r = 0; r < 4; ++r) lf[r] = 1.0f / lsum4[r];
  const size_t orow = (size_t)b * S + qt * 128 + w * 16 + lo * 4;
#pragma unroll
  for (int nj = 0; nj < 4; ++nj) {
    const int col = h * 64 + nj * 16 + lr;
#pragma unroll
    for (int r = 0; r < 4; ++r)
      Oa[(orow + r) * 2048 + col] = f2bf(acc[nj][r] * lf[r]);
  }
}

// ---------------- host ----------------
extern "C" void kernel_launch(void* const* d_in, const int* in_sizes, int n_in,
                              void* d_out, int out_size, void* d_ws, size_t ws_size,
                              hipStream_t stream) {
  const float* x  = (const float*)d_in[0];
  const float* Wq = (const float*)d_in[1];
  const float* bq = (const float*)d_in[2];
  const float* Wk = (const float*)d_in[3];
  const float* bk = (const float*)d_in[4];
  const float* Wv = (const float*)d_in[5];
  const float* bv = (const float*)d_in[6];
  const float* Wo = (const float*)d_in[7];
  const float* bo = (const float*)d_in[8];
  float* out = (float*)d_out;
  char* ws = (char*)d_ws;

  u16*   xb    = (u16*)(ws + 0);           // [4096][2048] bf16   16.78 MB
  u16*   wqkvT = (u16*)(ws + 16777216);    // [3072][2048] bf16   12.58 MB
  u16*   woT   = (u16*)(ws + 29360128);    // [2048][2048] bf16    8.39 MB
  u16*   qkv   = (u16*)(ws + 37748736);    // [4096][2560] bf16   20.97 MB (Q|K only)
  u16*   attn  = (u16*)(ws + 58720256);    // [4096][2048] bf16   16.78 MB
  u16*   vtg   = (u16*)(ws + 75497472);    // [2][8][64][2048] bf16 4.19 MB (V transposed)

  const float SCL = 0.125f * 1.44269504088896341f;  // 1/sqrt(64) * log2(e)

  k_prep<<<dim3(32, 32, 8), 256, 0, stream>>>(x, xb, Wq, Wk, Wv, Wo, wqkvT, woT);
  // QKV GEMM: C cols [0,2560) -> qkv (ldC=2560); cols [2560,3072) -> vtg transposed
  k_gemm<false><<<dim3(24, 32), 256, 0, stream>>>(xb, wqkvT, bq, bk, bv, qkv,
                                                  4096, 3072, 2048, 2048, 2560, 2048, SCL,
                                                  vtg, 2560, 2560);
  k_attn<<<dim3(16, 32, 2), 512, 0, stream>>>(qkv, vtg, attn);
  k_gemm<true><<<dim3(16, 32), 256, 0, stream>>>(attn, woT, bo, bo, bo, out,
                                                 4096, 2048, 2048, 2048, 4096, 0, 1.0f,
                                                 nullptr, 1 << 30, 2048);
}